// Round 1
// baseline (1217.473 us; speedup 1.0000x reference)
//
#include <hip/hip_runtime.h>

#define NN 100000
#define NE 1600000

// ---------------- CSR build ----------------

__global__ void k_count(const int* __restrict__ dst, int* __restrict__ deg, int E) {
    int e = blockIdx.x * blockDim.x + threadIdx.x;
    if (e < E) atomicAdd(&deg[dst[e]], 1);
}

__global__ __launch_bounds__(1024) void k_scan1(const int* __restrict__ deg,
                                                int* __restrict__ excl,
                                                int* __restrict__ sums, int N) {
    __shared__ int s[1024];
    int i = blockIdx.x * 1024 + threadIdx.x;
    int v = (i < N) ? deg[i] : 0;
    s[threadIdx.x] = v;
    __syncthreads();
    for (int off = 1; off < 1024; off <<= 1) {
        int t = (threadIdx.x >= (unsigned)off) ? s[threadIdx.x - off] : 0;
        __syncthreads();
        s[threadIdx.x] += t;
        __syncthreads();
    }
    if (i < N) excl[i] = s[threadIdx.x] - v;           // exclusive within block
    if (threadIdx.x == 1023) sums[blockIdx.x] = s[1023]; // block total
}

__global__ __launch_bounds__(128) void k_scan2(int* __restrict__ sums, int NB) {
    __shared__ int s[128];
    int v = (threadIdx.x < (unsigned)NB) ? sums[threadIdx.x] : 0;
    s[threadIdx.x] = v;
    __syncthreads();
    for (int off = 1; off < 128; off <<= 1) {
        int t = (threadIdx.x >= (unsigned)off) ? s[threadIdx.x - off] : 0;
        __syncthreads();
        s[threadIdx.x] += t;
        __syncthreads();
    }
    if (threadIdx.x < (unsigned)NB) sums[threadIdx.x] = s[threadIdx.x] - v; // exclusive
}

__global__ void k_finalize(int* __restrict__ offs, const int* __restrict__ sums,
                           const int* __restrict__ deg, int* __restrict__ cursor,
                           float* __restrict__ dinv, int N) {
    int i = blockIdx.x * blockDim.x + threadIdx.x;
    if (i < N) {
        int o = offs[i] + sums[i >> 10];
        offs[i] = o;
        cursor[i] = o;
        int d = deg[i];
        dinv[i] = 1.0f / (float)(d > 0 ? d : 1);
    }
}

__global__ void k_scatter(const int* __restrict__ src, const int* __restrict__ dst,
                          int* __restrict__ cursor, int* __restrict__ csr, int E) {
    int e = blockIdx.x * blockDim.x + threadIdx.x;
    if (e < E) {
        int pos = atomicAdd(&cursor[dst[e]], 1);
        csr[pos] = src[e];
    }
}

// ---------------- fp32 GEMM: C[N x Fo] = A[N x 128] @ W[128 x Fo] ----------------
// Block: 256 threads, tile 64 rows x 64 cols, K=128 fully staged in LDS.

__global__ __launch_bounds__(256) void k_gemm(const float* __restrict__ A,
                                              const float* __restrict__ W,
                                              float* __restrict__ C, int N, int Fo) {
    __shared__ float As[64][128];
    __shared__ float Wls[128][64];
    int tid = threadIdx.x;
    int row0 = blockIdx.x * 64;
    int colBase = blockIdx.y * 64;

    // A tile: 64x128 floats = 2048 float4, 8 per thread, coalesced
    for (int i = tid; i < 64 * 32; i += 256) {
        int r = i >> 5, c4 = (i & 31) << 2;
        int row = row0 + r;
        float4 v = make_float4(0.f, 0.f, 0.f, 0.f);
        if (row < N) v = *(const float4*)(A + (size_t)row * 128 + c4);
        *(float4*)&As[r][c4] = v;
    }
    // W tile: 128 x 64 (guarded for Fo=47)
    for (int i = tid; i < 128 * 16; i += 256) {
        int k = i >> 4, c4 = (i & 15) << 2;
        int c = colBase + c4;
        float4 w;
        if (((Fo & 3) == 0) && (c + 3 < Fo)) {
            w = *(const float4*)(W + (size_t)k * Fo + c);
        } else {
            float t0 = (c + 0 < Fo) ? W[(size_t)k * Fo + c + 0] : 0.f;
            float t1 = (c + 1 < Fo) ? W[(size_t)k * Fo + c + 1] : 0.f;
            float t2 = (c + 2 < Fo) ? W[(size_t)k * Fo + c + 2] : 0.f;
            float t3 = (c + 3 < Fo) ? W[(size_t)k * Fo + c + 3] : 0.f;
            w = make_float4(t0, t1, t2, t3);
        }
        *(float4*)&Wls[k][c4] = w;
    }
    __syncthreads();

    int tx = tid & 15, ty = tid >> 4;
    int r0 = ty << 2;
    float acc[4][4];
#pragma unroll
    for (int i = 0; i < 4; ++i)
#pragma unroll
        for (int j = 0; j < 4; ++j) acc[i][j] = 0.f;

#pragma unroll 4
    for (int k = 0; k < 128; ++k) {
        float4 w = *(float4*)&Wls[k][tx << 2];
        float a[4];
#pragma unroll
        for (int i = 0; i < 4; ++i) a[i] = As[r0 + i][k];
#pragma unroll
        for (int i = 0; i < 4; ++i) {
            acc[i][0] += a[i] * w.x;
            acc[i][1] += a[i] * w.y;
            acc[i][2] += a[i] * w.z;
            acc[i][3] += a[i] * w.w;
        }
    }

    int col = colBase + (tx << 2);
#pragma unroll
    for (int i = 0; i < 4; ++i) {
        int row = row0 + r0 + i;
        if (row >= N) continue;
        if ((Fo & 3) == 0) {
            *(float4*)(C + (size_t)row * Fo + col) =
                make_float4(acc[i][0], acc[i][1], acc[i][2], acc[i][3]);
        } else {
#pragma unroll
            for (int j = 0; j < 4; ++j)
                if (col + j < Fo) C[(size_t)row * Fo + col + j] = acc[i][j];
        }
    }
}

// ---------------- combine: out[v] = act(hs[v] + dinv[v]*sum_{u in N(v)} hw[u] + b) --------
// One wave (64 lanes) per node; lane = feature (and feature+64 for FO=128).

template <int FO, bool RELU>
__global__ __launch_bounds__(256) void k_combine(const float* __restrict__ hs,
                                                 const float* __restrict__ hw,
                                                 const int* __restrict__ csr,
                                                 const int* __restrict__ offs,
                                                 const int* __restrict__ deg,
                                                 const float* __restrict__ dinv,
                                                 const float* __restrict__ b,
                                                 float* __restrict__ out, int N) {
    int wid = (blockIdx.x * 256 + threadIdx.x) >> 6;
    int lane = threadIdx.x & 63;
    if (wid >= N) return;
    int beg = offs[wid];
    int d = deg[wid];
    if (FO == 128) {
        float acc0 = 0.f, acc1 = 0.f;
        for (int e = 0; e < d; ++e) {
            int u = csr[beg + e];
            const float* p = hw + (size_t)u * 128;
            acc0 += p[lane];
            acc1 += p[lane + 64];
        }
        float di = dinv[wid];
        float v0 = hs[(size_t)wid * 128 + lane] + di * acc0 + b[lane];
        float v1 = hs[(size_t)wid * 128 + lane + 64] + di * acc1 + b[lane + 64];
        if (RELU) { v0 = fmaxf(v0, 0.f); v1 = fmaxf(v1, 0.f); }
        out[(size_t)wid * 128 + lane] = v0;
        out[(size_t)wid * 128 + lane + 64] = v1;
    } else {
        if (lane >= FO) return;
        float acc = 0.f;
        for (int e = 0; e < d; ++e) {
            int u = csr[beg + e];
            acc += hw[(size_t)u * FO + lane];
        }
        float v = hs[(size_t)wid * FO + lane] + dinv[wid] * acc + b[lane];
        if (RELU) v = fmaxf(v, 0.f);
        out[(size_t)wid * FO + lane] = v;
    }
}

// ---------------- launch ----------------

extern "C" void kernel_launch(void* const* d_in, const int* in_sizes, int n_in,
                              void* d_out, int out_size, void* d_ws, size_t ws_size,
                              hipStream_t stream) {
    const int N = NN, E = NE;
    const float* x   = (const float*)d_in[0];
    const int*   src = (const int*)d_in[1];
    const int*   dst = (const int*)d_in[2];
    const float* Ws0 = (const float*)d_in[3];
    const float* Wn0 = (const float*)d_in[4];
    const float* b0  = (const float*)d_in[5];
    const float* Ws1 = (const float*)d_in[6];
    const float* Wn1 = (const float*)d_in[7];
    const float* b1  = (const float*)d_in[8];
    const float* Ws2 = (const float*)d_in[9];
    const float* Wn2 = (const float*)d_in[10];
    const float* b2  = (const float*)d_in[11];
    float* out = (float*)d_out;

    char* p = (char*)d_ws;
    size_t o = 0;
    auto alloc = [&](size_t bytes) -> void* {
        void* q = p + o;
        o = (o + bytes + 511) & ~(size_t)511;
        return q;
    };
    int*   deg    = (int*)alloc((size_t)N * 4);
    int*   offs   = (int*)alloc((size_t)N * 4);
    int*   cursor = (int*)alloc((size_t)N * 4);
    float* dinv   = (float*)alloc((size_t)N * 4);
    int*   sums   = (int*)alloc(1024 * 4);
    int*   csr    = (int*)alloc((size_t)E * 4);
    float* hA     = (float*)alloc((size_t)N * 128 * 4);
    float* hs     = (float*)alloc((size_t)N * 128 * 4);
    float* hw     = (float*)alloc((size_t)N * 128 * 4);

    // ---- CSR build (deg must be zeroed; ws is poisoned 0xAA each call) ----
    hipMemsetAsync(deg, 0, (size_t)N * 4, stream);
    k_count<<<(E + 255) / 256, 256, 0, stream>>>(dst, deg, E);
    int nb = (N + 1023) / 1024;  // 98 (<=128 for k_scan2)
    k_scan1<<<nb, 1024, 0, stream>>>(deg, offs, sums, N);
    k_scan2<<<1, 128, 0, stream>>>(sums, nb);
    k_finalize<<<(N + 255) / 256, 256, 0, stream>>>(offs, sums, deg, cursor, dinv, N);
    k_scatter<<<(E + 255) / 256, 256, 0, stream>>>(src, dst, cursor, csr, E);

    dim3 g128((N + 63) / 64, 2);
    dim3 g47((N + 63) / 64, 1);
    int cwg = (N * 64 + 255) / 256;  // one wave per node

    // ---- layer 0: transform-then-aggregate (mean commutes with linear map) ----
    k_gemm<<<g128, 256, 0, stream>>>(x, Ws0, hs, N, 128);
    k_gemm<<<g128, 256, 0, stream>>>(x, Wn0, hw, N, 128);
    k_combine<128, true><<<cwg, 256, 0, stream>>>(hs, hw, csr, offs, deg, dinv, b0, hA, N);

    // ---- layer 1 ----
    k_gemm<<<g128, 256, 0, stream>>>(hA, Ws1, hs, N, 128);
    k_gemm<<<g128, 256, 0, stream>>>(hA, Wn1, hw, N, 128);
    k_combine<128, true><<<cwg, 256, 0, stream>>>(hs, hw, csr, offs, deg, dinv, b1, hA, N);

    // ---- layer 2 (Fo=47) ----
    k_gemm<<<g47, 256, 0, stream>>>(hA, Ws2, hs, N, 47);
    k_gemm<<<g47, 256, 0, stream>>>(hA, Wn2, hw, N, 47);
    k_combine<47, false><<<cwg, 256, 0, stream>>>(hs, hw, csr, offs, deg, dinv, b2, out, N);
}

// Round 2
// 1178.830 us; speedup vs baseline: 1.0328x; 1.0328x over previous
//
#include <hip/hip_runtime.h>
#include <hip/hip_fp16.h>

#define NN 100000
#define NE 1600000

// ---------------- CSR build ----------------

__global__ void k_count(const int* __restrict__ dst, int* __restrict__ deg, int E) {
    int e = blockIdx.x * blockDim.x + threadIdx.x;
    if (e < E) atomicAdd(&deg[dst[e]], 1);
}

__global__ __launch_bounds__(1024) void k_scan1(const int* __restrict__ deg,
                                                int* __restrict__ excl,
                                                int* __restrict__ sums, int N) {
    __shared__ int s[1024];
    int i = blockIdx.x * 1024 + threadIdx.x;
    int v = (i < N) ? deg[i] : 0;
    s[threadIdx.x] = v;
    __syncthreads();
    for (int off = 1; off < 1024; off <<= 1) {
        int t = (threadIdx.x >= (unsigned)off) ? s[threadIdx.x - off] : 0;
        __syncthreads();
        s[threadIdx.x] += t;
        __syncthreads();
    }
    if (i < N) excl[i] = s[threadIdx.x] - v;             // exclusive within block
    if (threadIdx.x == 1023) sums[blockIdx.x] = s[1023]; // block total
}

__global__ __launch_bounds__(128) void k_scan2(int* __restrict__ sums, int NB) {
    __shared__ int s[128];
    int v = (threadIdx.x < (unsigned)NB) ? sums[threadIdx.x] : 0;
    s[threadIdx.x] = v;
    __syncthreads();
    for (int off = 1; off < 128; off <<= 1) {
        int t = (threadIdx.x >= (unsigned)off) ? s[threadIdx.x - off] : 0;
        __syncthreads();
        s[threadIdx.x] += t;
        __syncthreads();
    }
    if (threadIdx.x < (unsigned)NB) sums[threadIdx.x] = s[threadIdx.x] - v; // exclusive
}

__global__ void k_finalize(int* __restrict__ offs, const int* __restrict__ sums,
                           const int* __restrict__ deg, int* __restrict__ cursor,
                           float* __restrict__ dinv, int N) {
    int i = blockIdx.x * blockDim.x + threadIdx.x;
    if (i < N) {
        int o = offs[i] + sums[i >> 10];
        offs[i] = o;
        cursor[i] = o;
        int d = deg[i];
        dinv[i] = 1.0f / (float)(d > 0 ? d : 1);
    }
}

__global__ void k_scatter(const int* __restrict__ src, const int* __restrict__ dst,
                          int* __restrict__ cursor, int* __restrict__ csr, int E) {
    int e = blockIdx.x * blockDim.x + threadIdx.x;
    if (e < E) {
        int pos = atomicAdd(&cursor[dst[e]], 1);
        csr[pos] = src[e];
    }
}

// ---------------- dual fp32 GEMM ----------------
// One dispatch computes BOTH:
//   hs[N x Fo]    (fp32) = A @ Wself + b      (self path, bias folded)
//   hw[N x FoPad] (fp16) = A @ Wneigh         (neighbor path, zero-padded)
// Block: 256 threads, 64x64 tile, K=128 staged in LDS.
// gridDim.y = 2*ntiles; y < ntiles -> self, else neighbor.

__global__ __launch_bounds__(256) void k_gemm_dual(const float* __restrict__ A,
                                                   const float* __restrict__ Wself,
                                                   const float* __restrict__ Wneigh,
                                                   const float* __restrict__ bias,
                                                   float* __restrict__ hs,
                                                   __half* __restrict__ hw,
                                                   int N, int Fo, int FoPad) {
    __shared__ float As[64][128];
    __shared__ float Wls[128][64];
    int tid = threadIdx.x;
    int row0 = blockIdx.x * 64;
    int ntiles = gridDim.y >> 1;
    bool selfPath = (int)blockIdx.y < ntiles;
    int colBase = ((int)blockIdx.y % ntiles) * 64;
    const float* W = selfPath ? Wself : Wneigh;

    // A tile: 64x128 floats, float4 coalesced
    for (int i = tid; i < 64 * 32; i += 256) {
        int r = i >> 5, c4 = (i & 31) << 2;
        int row = row0 + r;
        float4 v = make_float4(0.f, 0.f, 0.f, 0.f);
        if (row < N) v = *(const float4*)(A + (size_t)row * 128 + c4);
        *(float4*)&As[r][c4] = v;
    }
    // W tile: 128 x 64 (guarded for Fo=47)
    for (int i = tid; i < 128 * 16; i += 256) {
        int k = i >> 4, c4 = (i & 15) << 2;
        int c = colBase + c4;
        float4 w;
        if (((Fo & 3) == 0) && (c + 3 < Fo)) {
            w = *(const float4*)(W + (size_t)k * Fo + c);
        } else {
            float t0 = (c + 0 < Fo) ? W[(size_t)k * Fo + c + 0] : 0.f;
            float t1 = (c + 1 < Fo) ? W[(size_t)k * Fo + c + 1] : 0.f;
            float t2 = (c + 2 < Fo) ? W[(size_t)k * Fo + c + 2] : 0.f;
            float t3 = (c + 3 < Fo) ? W[(size_t)k * Fo + c + 3] : 0.f;
            w = make_float4(t0, t1, t2, t3);
        }
        *(float4*)&Wls[k][c4] = w;
    }
    __syncthreads();

    int tx = tid & 15, ty = tid >> 4;
    int r0 = ty << 2;
    float acc[4][4];
#pragma unroll
    for (int i = 0; i < 4; ++i)
#pragma unroll
        for (int j = 0; j < 4; ++j) acc[i][j] = 0.f;

#pragma unroll 4
    for (int k = 0; k < 128; ++k) {
        float4 w = *(float4*)&Wls[k][tx << 2];
        float a[4];
#pragma unroll
        for (int i = 0; i < 4; ++i) a[i] = As[r0 + i][k];
#pragma unroll
        for (int i = 0; i < 4; ++i) {
            acc[i][0] += a[i] * w.x;
            acc[i][1] += a[i] * w.y;
            acc[i][2] += a[i] * w.z;
            acc[i][3] += a[i] * w.w;
        }
    }

    int col = colBase + (tx << 2);
    if (selfPath) {
#pragma unroll
        for (int i = 0; i < 4; ++i) {
            int row = row0 + r0 + i;
            if (row >= N) continue;
            if ((Fo & 3) == 0) {
                float b0 = bias[col], b1 = bias[col + 1], b2 = bias[col + 2], b3 = bias[col + 3];
                *(float4*)(hs + (size_t)row * Fo + col) =
                    make_float4(acc[i][0] + b0, acc[i][1] + b1, acc[i][2] + b2, acc[i][3] + b3);
            } else {
#pragma unroll
                for (int j = 0; j < 4; ++j)
                    if (col + j < Fo) hs[(size_t)row * Fo + col + j] = acc[i][j] + bias[col + j];
            }
        }
    } else {
        if (col < FoPad) {  // FoPad % 4 == 0, col % 4 == 0 -> col+3 < FoPad
#pragma unroll
            for (int i = 0; i < 4; ++i) {
                int row = row0 + r0 + i;
                if (row >= N) continue;
                float v0 = (col + 0 < Fo) ? acc[i][0] : 0.f;
                float v1 = (col + 1 < Fo) ? acc[i][1] : 0.f;
                float v2 = (col + 2 < Fo) ? acc[i][2] : 0.f;
                float v3 = (col + 3 < Fo) ? acc[i][3] : 0.f;
                __half2* dst2 = (__half2*)(hw + (size_t)row * FoPad + col);
                dst2[0] = __floats2half2_rn(v0, v1);
                dst2[1] = __floats2half2_rn(v2, v3);
            }
        }
    }
}

// ---------------- combine: out[v] = act(hs[v] + dinv[v]*sum_{u in N(v)} hw[u]) ----------
// One wave per node. hw is fp16, FoPad-wide; lane covers feature pair (2l, 2l+1).

template <int FOPAD, int FO, bool RELU>
__global__ __launch_bounds__(256) void k_combine(const float* __restrict__ hs,
                                                 const __half2* __restrict__ hw,
                                                 const int* __restrict__ csr,
                                                 const int* __restrict__ offs,
                                                 const int* __restrict__ deg,
                                                 const float* __restrict__ dinv,
                                                 float* __restrict__ out, int N) {
    int wid = (blockIdx.x * 256 + threadIdx.x) >> 6;
    int lane = threadIdx.x & 63;
    if (wid >= N) return;
    int beg = offs[wid];
    int d = deg[wid];
    constexpr int HP = FOPAD / 2;  // half2s per row
    if (lane < HP) {
        float acc0 = 0.f, acc1 = 0.f;
        for (int e = 0; e < d; ++e) {
            int u = csr[beg + e];
            __half2 v = hw[(size_t)u * HP + lane];
            float2 c = __half22float2(v);
            acc0 += c.x;
            acc1 += c.y;
        }
        float di = dinv[wid];
        int f0 = lane * 2, f1 = lane * 2 + 1;
        if (FO == FOPAD) {
            const float2* hs2 = (const float2*)hs;
            float2 s = hs2[(size_t)wid * HP + lane];
            float v0 = s.x + di * acc0;
            float v1 = s.y + di * acc1;
            if (RELU) { v0 = fmaxf(v0, 0.f); v1 = fmaxf(v1, 0.f); }
            float2* o2 = (float2*)out;
            o2[(size_t)wid * HP + lane] = make_float2(v0, v1);
        } else {
            float v0 = hs[(size_t)wid * FO + f0] + di * acc0;
            if (RELU) v0 = fmaxf(v0, 0.f);
            out[(size_t)wid * FO + f0] = v0;
            if (f1 < FO) {
                float v1 = hs[(size_t)wid * FO + f1] + di * acc1;
                if (RELU) v1 = fmaxf(v1, 0.f);
                out[(size_t)wid * FO + f1] = v1;
            }
        }
    }
}

// ---------------- launch ----------------

extern "C" void kernel_launch(void* const* d_in, const int* in_sizes, int n_in,
                              void* d_out, int out_size, void* d_ws, size_t ws_size,
                              hipStream_t stream) {
    const int N = NN, E = NE;
    const float* x   = (const float*)d_in[0];
    const int*   src = (const int*)d_in[1];
    const int*   dst = (const int*)d_in[2];
    const float* Ws0 = (const float*)d_in[3];
    const float* Wn0 = (const float*)d_in[4];
    const float* b0  = (const float*)d_in[5];
    const float* Ws1 = (const float*)d_in[6];
    const float* Wn1 = (const float*)d_in[7];
    const float* b1  = (const float*)d_in[8];
    const float* Ws2 = (const float*)d_in[9];
    const float* Wn2 = (const float*)d_in[10];
    const float* b2  = (const float*)d_in[11];
    float* out = (float*)d_out;

    char* p = (char*)d_ws;
    size_t o = 0;
    auto alloc = [&](size_t bytes) -> void* {
        void* q = p + o;
        o = (o + bytes + 511) & ~(size_t)511;
        return q;
    };
    int*    deg    = (int*)alloc((size_t)N * 4);
    int*    offs   = (int*)alloc((size_t)N * 4);
    int*    cursor = (int*)alloc((size_t)N * 4);
    float*  dinv   = (float*)alloc((size_t)N * 4);
    int*    sums   = (int*)alloc(1024 * 4);
    int*    csr    = (int*)alloc((size_t)E * 4);
    float*  hA     = (float*)alloc((size_t)N * 128 * 4);
    float*  hs     = (float*)alloc((size_t)N * 128 * 4);
    __half* hw     = (__half*)alloc((size_t)N * 128 * 2);

    // ---- CSR build (deg must be zeroed; ws is poisoned 0xAA each call) ----
    hipMemsetAsync(deg, 0, (size_t)N * 4, stream);
    k_count<<<(E + 255) / 256, 256, 0, stream>>>(dst, deg, E);
    int nb = (N + 1023) / 1024;  // 98 (<=128 for k_scan2)
    k_scan1<<<nb, 1024, 0, stream>>>(deg, offs, sums, N);
    k_scan2<<<1, 128, 0, stream>>>(sums, nb);
    k_finalize<<<(N + 255) / 256, 256, 0, stream>>>(offs, sums, deg, cursor, dinv, N);
    k_scatter<<<(E + 255) / 256, 256, 0, stream>>>(src, dst, cursor, csr, E);

    dim3 g128((N + 63) / 64, 4);  // 2 col-tiles x {self, neigh}
    dim3 g47((N + 63) / 64, 2);   // 1 col-tile  x {self, neigh}
    int cwg = (N * 64 + 255) / 256;  // one wave per node

    // ---- layer 0 (transform-then-aggregate: mean commutes with linear map) ----
    k_gemm_dual<<<g128, 256, 0, stream>>>(x, Ws0, Wn0, b0, hs, hw, N, 128, 128);
    k_combine<128, 128, true><<<cwg, 256, 0, stream>>>(hs, (const __half2*)hw, csr, offs, deg, dinv, hA, N);

    // ---- layer 1 ----
    k_gemm_dual<<<g128, 256, 0, stream>>>(hA, Ws1, Wn1, b1, hs, hw, N, 128, 128);
    k_combine<128, 128, true><<<cwg, 256, 0, stream>>>(hs, (const __half2*)hw, csr, offs, deg, dinv, hA, N);

    // ---- layer 2 (Fo=47, hw padded to 48) ----
    k_gemm_dual<<<g47, 256, 0, stream>>>(hA, Ws2, Wn2, b2, hs, hw, N, 47, 48);
    k_combine<48, 47, false><<<cwg, 256, 0, stream>>>(hs, (const __half2*)hw, csr, offs, deg, dinv, out, N);
}

// Round 3
// 954.698 us; speedup vs baseline: 1.2752x; 1.2348x over previous
//
#include <hip/hip_runtime.h>
#include <hip/hip_fp16.h>

#define NN 100000
#define NE 1600000

typedef __attribute__((ext_vector_type(8))) short bf16x8;
typedef __attribute__((ext_vector_type(4))) float f32x4;
#define MFMA16(a, b, c) __builtin_amdgcn_mfma_f32_16x16x32_bf16(a, b, c, 0, 0, 0)

__device__ __forceinline__ short f2bf(float x) {
    union { float f; unsigned u; } v; v.f = x;
    unsigned r = v.u + 0x7FFF + ((v.u >> 16) & 1);  // RN-even
    return (short)(r >> 16);
}
__device__ __forceinline__ float bf2f(short h) {
    union { float f; unsigned u; } v; v.u = ((unsigned)(unsigned short)h) << 16;
    return v.f;
}

// ---------------- CSR build ----------------

__global__ void k_count(const int* __restrict__ dst, int* __restrict__ deg, int E) {
    int e = blockIdx.x * blockDim.x + threadIdx.x;
    if (e < E) atomicAdd(&deg[dst[e]], 1);
}

__global__ __launch_bounds__(1024) void k_scan1(const int* __restrict__ deg,
                                                int* __restrict__ excl,
                                                int* __restrict__ sums, int N) {
    __shared__ int s[1024];
    int i = blockIdx.x * 1024 + threadIdx.x;
    int v = (i < N) ? deg[i] : 0;
    s[threadIdx.x] = v;
    __syncthreads();
    for (int off = 1; off < 1024; off <<= 1) {
        int t = (threadIdx.x >= (unsigned)off) ? s[threadIdx.x - off] : 0;
        __syncthreads();
        s[threadIdx.x] += t;
        __syncthreads();
    }
    if (i < N) excl[i] = s[threadIdx.x] - v;
    if (threadIdx.x == 1023) sums[blockIdx.x] = s[1023];
}

__global__ __launch_bounds__(128) void k_scan2(int* __restrict__ sums, int NB) {
    __shared__ int s[128];
    int v = (threadIdx.x < (unsigned)NB) ? sums[threadIdx.x] : 0;
    s[threadIdx.x] = v;
    __syncthreads();
    for (int off = 1; off < 128; off <<= 1) {
        int t = (threadIdx.x >= (unsigned)off) ? s[threadIdx.x - off] : 0;
        __syncthreads();
        s[threadIdx.x] += t;
        __syncthreads();
    }
    if (threadIdx.x < (unsigned)NB) sums[threadIdx.x] = s[threadIdx.x] - v;
}

__global__ void k_finalize(int* __restrict__ offs, const int* __restrict__ sums,
                           const int* __restrict__ deg, int* __restrict__ cursor,
                           float* __restrict__ dinv, int N) {
    int i = blockIdx.x * blockDim.x + threadIdx.x;
    if (i < N) {
        int o = offs[i] + sums[i >> 10];
        offs[i] = o;
        cursor[i] = o;
        int d = deg[i];
        dinv[i] = 1.0f / (float)(d > 0 ? d : 1);
    }
}

__global__ void k_scatter(const int* __restrict__ src, const int* __restrict__ dst,
                          int* __restrict__ cursor, int* __restrict__ csr, int E) {
    int e = blockIdx.x * blockDim.x + threadIdx.x;
    if (e < E) {
        int pos = atomicAdd(&cursor[dst[e]], 1);
        csr[pos] = src[e];
    }
}

// ---------------- pack W into B-fragment order, bf16 hi/lo split ----------------
// B-frag for mfma_f32_16x16x32_bf16: lane l holds B[k = c*32 + (l>>4)*8 + j][n = ct*16 + (l&15)]
// packed elem index: ((ct*4 + c)*64 + lane)*8 + j

__global__ void k_packW(const float* __restrict__ W0, const float* __restrict__ W1,
                        const float* __restrict__ W2, const float* __restrict__ W3,
                        const float* __restrict__ W4, const float* __restrict__ W5,
                        short* __restrict__ Whi, short* __restrict__ Wlo) {
    int m = blockIdx.y;
    const float* W; int Fo, nct, off;
    switch (m) {
        case 0: W = W0; Fo = 128; nct = 8; off = 0;     break;
        case 1: W = W1; Fo = 128; nct = 8; off = 16384; break;
        case 2: W = W2; Fo = 128; nct = 8; off = 32768; break;
        case 3: W = W3; Fo = 128; nct = 8; off = 49152; break;
        case 4: W = W4; Fo = 47;  nct = 3; off = 65536; break;
        default:W = W5; Fo = 47;  nct = 3; off = 71680; break;
    }
    int e = blockIdx.x * 256 + threadIdx.x;
    if (e >= nct * 2048) return;
    int j = e & 7, lane = (e >> 3) & 63, c = (e >> 9) & 3, ct = e >> 11;
    int k = c * 32 + (lane >> 4) * 8 + j;
    int n = ct * 16 + (lane & 15);
    float v = (n < Fo) ? W[(size_t)k * Fo + n] : 0.f;
    short h = f2bf(v);
    Whi[off + e] = h;
    Wlo[off + e] = f2bf(v - bf2f(h));
}

// ---------------- split A (fp32 row-major) into packed bf16 hi/lo A-frag order --------
// A-frag: lane l holds A[rowtile*16 + (l&15)][c*32 + (l>>4)*8 + j]
// packed elem index: ((rowtile*4 + c)*64 + lane)*8 + j

__global__ void k_splitA(const float* __restrict__ A, short* __restrict__ Ah,
                         short* __restrict__ Al, int N) {
    int t = blockIdx.x * 256 + threadIdx.x;
    if (t >= N * 64) return;
    int n = t >> 6;
    int kp = (t & 63) * 2;
    float2 v = *(const float2*)(A + (size_t)n * 128 + kp);
    int rt = n >> 4, mm = n & 15;
    int c = kp >> 5, q = (kp & 31) >> 3, j = kp & 7;
    size_t idx = ((size_t)(rt * 4 + c) * 64 + q * 16 + mm) * 8 + j;
    short h0 = f2bf(v.x), h1 = f2bf(v.y);
    *(short2*)(Ah + idx) = make_short2(h0, h1);
    *(short2*)(Al + idx) = make_short2(f2bf(v.x - bf2f(h0)), f2bf(v.y - bf2f(h1)));
}

// ---------------- MFMA dual GEMM, Fo=128 ----------------
// Block: 256 thr = 4 waves. 64 rows/block. wave: path = w>>1 (0 self, 1 neigh),
// col half = w&1. Each wave: 4 row-tiles x 4 col-tiles, split-bf16 (3 MFMA/tile/chunk).

__global__ __launch_bounds__(256) void k_gemm128(const short* __restrict__ Ah,
                                                 const short* __restrict__ Al,
                                                 const short* __restrict__ WsHi,
                                                 const short* __restrict__ WsLo,
                                                 const short* __restrict__ WnHi,
                                                 const short* __restrict__ WnLo,
                                                 const float* __restrict__ bias,
                                                 float* __restrict__ hs,
                                                 __half* __restrict__ hw, int N) {
    int tid = threadIdx.x;
    int w = tid >> 6, l = tid & 63;
    int rb = blockIdx.x, row0 = rb * 64;
    int path = w >> 1, cg = w & 1;
    const short* BH = path ? WnHi : WsHi;
    const short* BL = path ? WnLo : WsLo;

    f32x4 acc[4][4];
#pragma unroll
    for (int i = 0; i < 4; ++i)
#pragma unroll
        for (int j = 0; j < 4; ++j) acc[i][j] = (f32x4){0.f, 0.f, 0.f, 0.f};

#pragma unroll
    for (int c = 0; c < 4; ++c) {
        bf16x8 ah[4], al[4], bh[4], bl[4];
#pragma unroll
        for (int rt = 0; rt < 4; ++rt) {
            size_t ai = (((size_t)(rb * 4 + rt) * 4 + c) * 64 + l) * 8;
            ah[rt] = *(const bf16x8*)(Ah + ai);
            al[rt] = *(const bf16x8*)(Al + ai);
        }
#pragma unroll
        for (int ct = 0; ct < 4; ++ct) {
            size_t bi = (((size_t)(cg * 4 + ct) * 4 + c) * 64 + l) * 8;
            bh[ct] = *(const bf16x8*)(BH + bi);
            bl[ct] = *(const bf16x8*)(BL + bi);
        }
#pragma unroll
        for (int rt = 0; rt < 4; ++rt)
#pragma unroll
            for (int ct = 0; ct < 4; ++ct) {
                acc[rt][ct] = MFMA16(ah[rt], bh[ct], acc[rt][ct]);
                acc[rt][ct] = MFMA16(ah[rt], bl[ct], acc[rt][ct]);
                acc[rt][ct] = MFMA16(al[rt], bh[ct], acc[rt][ct]);
            }
    }

    // C/D layout: col = l&15, row = (l>>4)*4 + r   [verified m89/m91]
    int q = l >> 4, n15 = l & 15;
#pragma unroll
    for (int ct = 0; ct < 4; ++ct) {
        int col = (cg * 4 + ct) * 16 + n15;
        float b = (path == 0) ? bias[col] : 0.f;
#pragma unroll
        for (int rt = 0; rt < 4; ++rt) {
            int rbase = row0 + rt * 16 + q * 4;
#pragma unroll
            for (int r = 0; r < 4; ++r) {
                int row = rbase + r;
                if (row >= N) continue;
                if (path == 0)
                    hs[(size_t)row * 128 + col] = acc[rt][ct][r] + b;
                else
                    hw[(size_t)row * 128 + col] = __float2half(acc[rt][ct][r]);
            }
        }
    }
}

// ---------------- MFMA dual GEMM, Fo=47 (padded 48) ----------------
// Block covers 128 rows: wave: path = w&1, rowgroup = w>>1. 4 row-tiles x 3 col-tiles.

__global__ __launch_bounds__(256) void k_gemm47(const short* __restrict__ Ah,
                                                const short* __restrict__ Al,
                                                const short* __restrict__ WsHi,
                                                const short* __restrict__ WsLo,
                                                const short* __restrict__ WnHi,
                                                const short* __restrict__ WnLo,
                                                const float* __restrict__ bias,
                                                float* __restrict__ hs,
                                                __half* __restrict__ hw, int N) {
    int tid = threadIdx.x;
    int w = tid >> 6, l = tid & 63;
    int rb = blockIdx.x;
    int path = w & 1, rg = w >> 1;
    int row0 = rb * 128 + rg * 64;
    const short* BH = path ? WnHi : WsHi;
    const short* BL = path ? WnLo : WsLo;

    f32x4 acc[4][3];
#pragma unroll
    for (int i = 0; i < 4; ++i)
#pragma unroll
        for (int j = 0; j < 3; ++j) acc[i][j] = (f32x4){0.f, 0.f, 0.f, 0.f};

#pragma unroll
    for (int c = 0; c < 4; ++c) {
        bf16x8 ah[4], al[4], bh[3], bl[3];
#pragma unroll
        for (int rt = 0; rt < 4; ++rt) {
            size_t ai = (((size_t)(rb * 8 + rg * 4 + rt) * 4 + c) * 64 + l) * 8;
            ah[rt] = *(const bf16x8*)(Ah + ai);
            al[rt] = *(const bf16x8*)(Al + ai);
        }
#pragma unroll
        for (int ct = 0; ct < 3; ++ct) {
            size_t bi = (((size_t)ct * 4 + c) * 64 + l) * 8;
            bh[ct] = *(const bf16x8*)(BH + bi);
            bl[ct] = *(const bf16x8*)(BL + bi);
        }
#pragma unroll
        for (int rt = 0; rt < 4; ++rt)
#pragma unroll
            for (int ct = 0; ct < 3; ++ct) {
                acc[rt][ct] = MFMA16(ah[rt], bh[ct], acc[rt][ct]);
                acc[rt][ct] = MFMA16(ah[rt], bl[ct], acc[rt][ct]);
                acc[rt][ct] = MFMA16(al[rt], bh[ct], acc[rt][ct]);
            }
    }

    int q = l >> 4, n15 = l & 15;
#pragma unroll
    for (int ct = 0; ct < 3; ++ct) {
        int col = ct * 16 + n15;
        float b = (path == 0 && col < 47) ? bias[col] : 0.f;
#pragma unroll
        for (int rt = 0; rt < 4; ++rt) {
            int rbase = row0 + rt * 16 + q * 4;
#pragma unroll
            for (int r = 0; r < 4; ++r) {
                int row = rbase + r;
                if (row >= N) continue;
                if (path == 0) {
                    if (col < 47) hs[(size_t)row * 47 + col] = acc[rt][ct][r] + b;
                } else {
                    hw[(size_t)row * 48 + col] = __float2half(acc[rt][ct][r]);
                }
            }
        }
    }
}

// ---------------- combine (mid layers): relu, write packed bf16-split A for next GEMM --

__global__ __launch_bounds__(256) void k_combine_mid(const float* __restrict__ hs,
                                                     const __half2* __restrict__ hw,
                                                     const int* __restrict__ csr,
                                                     const int* __restrict__ offs,
                                                     const int* __restrict__ deg,
                                                     const float* __restrict__ dinv,
                                                     short* __restrict__ Ah,
                                                     short* __restrict__ Al, int N) {
    int wid = (blockIdx.x * 256 + threadIdx.x) >> 6;
    int l = threadIdx.x & 63;
    if (wid >= N) return;
    int beg = offs[wid], d = deg[wid];
    float acc0 = 0.f, acc1 = 0.f;
    for (int e = 0; e < d; ++e) {
        int u = csr[beg + e];
        float2 c = __half22float2(hw[(size_t)u * 64 + l]);
        acc0 += c.x;
        acc1 += c.y;
    }
    float di = dinv[wid];
    float2 s = ((const float2*)hs)[(size_t)wid * 64 + l];
    float v0 = fmaxf(s.x + di * acc0, 0.f);
    float v1 = fmaxf(s.y + di * acc1, 0.f);

    int rt = wid >> 4, mm = wid & 15;
    int k0 = l * 2;
    int c4 = k0 >> 5, q = (k0 & 31) >> 3, j = k0 & 7;
    size_t idx = ((size_t)(rt * 4 + c4) * 64 + q * 16 + mm) * 8 + j;
    short h0 = f2bf(v0), h1 = f2bf(v1);
    *(short2*)(Ah + idx) = make_short2(h0, h1);
    *(short2*)(Al + idx) = make_short2(f2bf(v0 - bf2f(h0)), f2bf(v1 - bf2f(h1)));
}

// ---------------- combine (final layer, Fo=47): fp32 row-major out, no relu ----------

__global__ __launch_bounds__(256) void k_combine_final(const float* __restrict__ hs,
                                                       const __half2* __restrict__ hw,
                                                       const int* __restrict__ csr,
                                                       const int* __restrict__ offs,
                                                       const int* __restrict__ deg,
                                                       const float* __restrict__ dinv,
                                                       float* __restrict__ out, int N) {
    int wid = (blockIdx.x * 256 + threadIdx.x) >> 6;
    int l = threadIdx.x & 63;
    if (wid >= N) return;
    if (l >= 24) return;  // 48/2 half2s
    int beg = offs[wid], d = deg[wid];
    float acc0 = 0.f, acc1 = 0.f;
    for (int e = 0; e < d; ++e) {
        int u = csr[beg + e];
        float2 c = __half22float2(hw[(size_t)u * 24 + l]);
        acc0 += c.x;
        acc1 += c.y;
    }
    float di = dinv[wid];
    int f0 = l * 2, f1 = l * 2 + 1;
    out[(size_t)wid * 47 + f0] = hs[(size_t)wid * 47 + f0] + di * acc0;
    if (f1 < 47) out[(size_t)wid * 47 + f1] = hs[(size_t)wid * 47 + f1] + di * acc1;
}

// ---------------- launch ----------------

extern "C" void kernel_launch(void* const* d_in, const int* in_sizes, int n_in,
                              void* d_out, int out_size, void* d_ws, size_t ws_size,
                              hipStream_t stream) {
    const int N = NN, E = NE;
    const float* x   = (const float*)d_in[0];
    const int*   src = (const int*)d_in[1];
    const int*   dst = (const int*)d_in[2];
    const float* Ws0 = (const float*)d_in[3];
    const float* Wn0 = (const float*)d_in[4];
    const float* b0  = (const float*)d_in[5];
    const float* Ws1 = (const float*)d_in[6];
    const float* Wn1 = (const float*)d_in[7];
    const float* b1  = (const float*)d_in[8];
    const float* Ws2 = (const float*)d_in[9];
    const float* Wn2 = (const float*)d_in[10];
    const float* b2  = (const float*)d_in[11];
    float* out = (float*)d_out;

    char* p = (char*)d_ws;
    size_t o = 0;
    auto alloc = [&](size_t bytes) -> void* {
        void* q = p + o;
        o = (o + bytes + 511) & ~(size_t)511;
        return q;
    };
    const size_t RTPAD = 6256;  // row-tiles of 16, padded to gemm47 block span (128 rows)
    int*    deg    = (int*)alloc((size_t)N * 4);
    int*    offs   = (int*)alloc((size_t)N * 4);
    int*    cursor = (int*)alloc((size_t)N * 4);
    float*  dinv   = (float*)alloc((size_t)N * 4);
    int*    sums   = (int*)alloc(1024 * 4);
    int*    csr    = (int*)alloc((size_t)E * 4);
    short*  Ahp    = (short*)alloc(RTPAD * 2048 * 2);
    short*  Alp    = (short*)alloc(RTPAD * 2048 * 2);
    float*  hs     = (float*)alloc((size_t)N * 128 * 4);
    __half* hw     = (__half*)alloc((size_t)N * 128 * 2);
    short*  Whi    = (short*)alloc(77824 * 2);
    short*  Wlo    = (short*)alloc(77824 * 2);

    // ---- CSR build ----
    hipMemsetAsync(deg, 0, (size_t)N * 4, stream);
    k_count<<<(E + 255) / 256, 256, 0, stream>>>(dst, deg, E);
    int nb = (N + 1023) / 1024;
    k_scan1<<<nb, 1024, 0, stream>>>(deg, offs, sums, N);
    k_scan2<<<1, 128, 0, stream>>>(sums, nb);
    k_finalize<<<(N + 255) / 256, 256, 0, stream>>>(offs, sums, deg, cursor, dinv, N);
    k_scatter<<<(E + 255) / 256, 256, 0, stream>>>(src, dst, cursor, csr, E);

    // ---- pack weights + split input ----
    k_packW<<<dim3(64, 6), 256, 0, stream>>>(Ws0, Wn0, Ws1, Wn1, Ws2, Wn2, Whi, Wlo);
    k_splitA<<<(N * 64 + 255) / 256, 256, 0, stream>>>(x, Ahp, Alp, N);

    int g128 = (N + 63) / 64;    // 1563
    int g47  = (N + 127) / 128;  // 782
    int cwg  = (N * 64 + 255) / 256;

    // ---- layer 0 ----
    k_gemm128<<<g128, 256, 0, stream>>>(Ahp, Alp, Whi, Wlo, Whi + 16384, Wlo + 16384,
                                        b0, hs, hw, N);
    k_combine_mid<<<cwg, 256, 0, stream>>>(hs, (const __half2*)hw, csr, offs, deg, dinv,
                                           Ahp, Alp, N);
    // ---- layer 1 ----
    k_gemm128<<<g128, 256, 0, stream>>>(Ahp, Alp, Whi + 32768, Wlo + 32768,
                                        Whi + 49152, Wlo + 49152, b1, hs, hw, N);
    k_combine_mid<<<cwg, 256, 0, stream>>>(hs, (const __half2*)hw, csr, offs, deg, dinv,
                                           Ahp, Alp, N);
    // ---- layer 2 (Fo=47, hw padded to 48) ----
    k_gemm47<<<g47, 256, 0, stream>>>(Ahp, Alp, Whi + 65536, Wlo + 65536,
                                      Whi + 71680, Wlo + 71680, b2, hs, hw, N);
    k_combine_final<<<cwg, 256, 0, stream>>>(hs, (const __half2*)hw, csr, offs, deg, dinv,
                                             out, N);
}

// Round 4
// 681.351 us; speedup vs baseline: 1.7869x; 1.4012x over previous
//
#include <hip/hip_runtime.h>
#include <hip/hip_fp16.h>

#define NN 100000
#define NE 1600000

typedef __attribute__((ext_vector_type(8))) short bf16x8;
typedef __attribute__((ext_vector_type(4))) float f32x4;
#define MFMA16(a, b, c) __builtin_amdgcn_mfma_f32_16x16x32_bf16(a, b, c, 0, 0, 0)

__device__ __forceinline__ short f2bf(float x) {
    union { float f; unsigned u; } v; v.f = x;
    unsigned r = v.u + 0x7FFF + ((v.u >> 16) & 1);  // RN-even
    return (short)(r >> 16);
}
__device__ __forceinline__ float bf2f(short h) {
    union { float f; unsigned u; } v; v.u = ((unsigned)(unsigned short)h) << 16;
    return v.f;
}

// ---------------- CSR build ----------------

__global__ void k_count(const int* __restrict__ dst, int* __restrict__ deg, int E) {
    int e = blockIdx.x * blockDim.x + threadIdx.x;
    if (e < E) atomicAdd(&deg[dst[e]], 1);
}

__global__ __launch_bounds__(1024) void k_scan1(const int* __restrict__ deg,
                                                int* __restrict__ excl,
                                                int* __restrict__ sums, int N) {
    __shared__ int s[1024];
    int i = blockIdx.x * 1024 + threadIdx.x;
    int v = (i < N) ? deg[i] : 0;
    s[threadIdx.x] = v;
    __syncthreads();
    for (int off = 1; off < 1024; off <<= 1) {
        int t = (threadIdx.x >= (unsigned)off) ? s[threadIdx.x - off] : 0;
        __syncthreads();
        s[threadIdx.x] += t;
        __syncthreads();
    }
    if (i < N) excl[i] = s[threadIdx.x] - v;
    if (threadIdx.x == 1023) sums[blockIdx.x] = s[1023];
}

__global__ __launch_bounds__(128) void k_scan2(int* __restrict__ sums, int NB) {
    __shared__ int s[128];
    int v = (threadIdx.x < (unsigned)NB) ? sums[threadIdx.x] : 0;
    s[threadIdx.x] = v;
    __syncthreads();
    for (int off = 1; off < 128; off <<= 1) {
        int t = (threadIdx.x >= (unsigned)off) ? s[threadIdx.x - off] : 0;
        __syncthreads();
        s[threadIdx.x] += t;
        __syncthreads();
    }
    if (threadIdx.x < (unsigned)NB) sums[threadIdx.x] = s[threadIdx.x] - v;
}

__global__ void k_finalize(int* __restrict__ offs, const int* __restrict__ sums,
                           const int* __restrict__ deg, int* __restrict__ cursor,
                           float* __restrict__ dinv, int N) {
    int i = blockIdx.x * blockDim.x + threadIdx.x;
    if (i < N) {
        int o = offs[i] + sums[i >> 10];
        offs[i] = o;
        cursor[i] = o;
        int d = deg[i];
        dinv[i] = 1.0f / (float)(d > 0 ? d : 1);
    }
}

__global__ void k_scatter(const int* __restrict__ src, const int* __restrict__ dst,
                          int* __restrict__ cursor, int* __restrict__ csr, int E) {
    int e = blockIdx.x * blockDim.x + threadIdx.x;
    if (e < E) {
        int pos = atomicAdd(&cursor[dst[e]], 1);
        csr[pos] = src[e];
    }
}

// ---------------- pack W into B-fragment order, bf16 hi/lo split ----------------
// B-frag: lane l holds B[k = c*32 + (l>>4)*8 + j][n = ct*16 + (l&15)]
// packed elem index: ((ct*4 + c)*64 + lane)*8 + j

__global__ void k_packW(const float* __restrict__ W0, const float* __restrict__ W1,
                        const float* __restrict__ W2, const float* __restrict__ W3,
                        const float* __restrict__ W4, const float* __restrict__ W5,
                        short* __restrict__ Whi, short* __restrict__ Wlo) {
    int m = blockIdx.y;
    const float* W; int Fo, nct, off;
    switch (m) {
        case 0: W = W0; Fo = 128; nct = 8; off = 0;     break;
        case 1: W = W1; Fo = 128; nct = 8; off = 16384; break;
        case 2: W = W2; Fo = 128; nct = 8; off = 32768; break;
        case 3: W = W3; Fo = 128; nct = 8; off = 49152; break;
        case 4: W = W4; Fo = 47;  nct = 3; off = 65536; break;
        default:W = W5; Fo = 47;  nct = 3; off = 71680; break;
    }
    int e = blockIdx.x * 256 + threadIdx.x;
    if (e >= nct * 2048) return;
    int j = e & 7, lane = (e >> 3) & 63, c = (e >> 9) & 3, ct = e >> 11;
    int k = c * 32 + (lane >> 4) * 8 + j;
    int n = ct * 16 + (lane & 15);
    float v = (n < Fo) ? W[(size_t)k * Fo + n] : 0.f;
    short h = f2bf(v);
    Whi[off + e] = h;
    Wlo[off + e] = f2bf(v - bf2f(h));
}

// ---------------- split A (fp32 row-major) into packed bf16 hi/lo A-frag order --------
// A-frag: lane l holds A[rowtile*16 + (l&15)][c*32 + (l>>4)*8 + j]
// packed elem index: ((rowtile*4 + c)*64 + lane)*8 + j

__global__ void k_splitA(const float* __restrict__ A, short* __restrict__ Ah,
                         short* __restrict__ Al, int N) {
    int t = blockIdx.x * 256 + threadIdx.x;
    if (t >= N * 64) return;
    int n = t >> 6;
    int kp = (t & 63) * 2;
    float2 v = *(const float2*)(A + (size_t)n * 128 + kp);
    int rt = n >> 4, mm = n & 15;
    int c = kp >> 5, q = (kp & 31) >> 3, j = kp & 7;
    size_t idx = ((size_t)(rt * 4 + c) * 64 + q * 16 + mm) * 8 + j;
    short h0 = f2bf(v.x), h1 = f2bf(v.y);
    *(short2*)(Ah + idx) = make_short2(h0, h1);
    *(short2*)(Al + idx) = make_short2(f2bf(v.x - bf2f(h0)), f2bf(v.y - bf2f(h1)));
}

// ---------------- MFMA dual GEMM, Fo=128 ----------------

__global__ __launch_bounds__(256) void k_gemm128(const short* __restrict__ Ah,
                                                 const short* __restrict__ Al,
                                                 const short* __restrict__ WsHi,
                                                 const short* __restrict__ WsLo,
                                                 const short* __restrict__ WnHi,
                                                 const short* __restrict__ WnLo,
                                                 const float* __restrict__ bias,
                                                 float* __restrict__ hs,
                                                 __half* __restrict__ hw, int N) {
    int tid = threadIdx.x;
    int w = tid >> 6, l = tid & 63;
    int rb = blockIdx.x, row0 = rb * 64;
    int path = w >> 1, cg = w & 1;
    const short* BH = path ? WnHi : WsHi;
    const short* BL = path ? WnLo : WsLo;

    f32x4 acc[4][4];
#pragma unroll
    for (int i = 0; i < 4; ++i)
#pragma unroll
        for (int j = 0; j < 4; ++j) acc[i][j] = (f32x4){0.f, 0.f, 0.f, 0.f};

#pragma unroll
    for (int c = 0; c < 4; ++c) {
        bf16x8 ah[4], al[4], bh[4], bl[4];
#pragma unroll
        for (int rt = 0; rt < 4; ++rt) {
            size_t ai = (((size_t)(rb * 4 + rt) * 4 + c) * 64 + l) * 8;
            ah[rt] = *(const bf16x8*)(Ah + ai);
            al[rt] = *(const bf16x8*)(Al + ai);
        }
#pragma unroll
        for (int ct = 0; ct < 4; ++ct) {
            size_t bi = (((size_t)(cg * 4 + ct) * 4 + c) * 64 + l) * 8;
            bh[ct] = *(const bf16x8*)(BH + bi);
            bl[ct] = *(const bf16x8*)(BL + bi);
        }
#pragma unroll
        for (int rt = 0; rt < 4; ++rt)
#pragma unroll
            for (int ct = 0; ct < 4; ++ct) {
                acc[rt][ct] = MFMA16(ah[rt], bh[ct], acc[rt][ct]);
                acc[rt][ct] = MFMA16(ah[rt], bl[ct], acc[rt][ct]);
                acc[rt][ct] = MFMA16(al[rt], bh[ct], acc[rt][ct]);
            }
    }

    // C/D layout: col = l&15, row = (l>>4)*4 + r   [verified m89/m91]
    int q = l >> 4, n15 = l & 15;
#pragma unroll
    for (int ct = 0; ct < 4; ++ct) {
        int col = (cg * 4 + ct) * 16 + n15;
        float b = (path == 0) ? bias[col] : 0.f;
#pragma unroll
        for (int rt = 0; rt < 4; ++rt) {
            int rbase = row0 + rt * 16 + q * 4;
#pragma unroll
            for (int r = 0; r < 4; ++r) {
                int row = rbase + r;
                if (row >= N) continue;
                if (path == 0)
                    hs[(size_t)row * 128 + col] = acc[rt][ct][r] + b;
                else
                    hw[(size_t)row * 128 + col] = __float2half(acc[rt][ct][r]);
            }
        }
    }
}

// ---------------- MFMA dual GEMM, Fo=47 (padded 48) ----------------

__global__ __launch_bounds__(256) void k_gemm47(const short* __restrict__ Ah,
                                                const short* __restrict__ Al,
                                                const short* __restrict__ WsHi,
                                                const short* __restrict__ WsLo,
                                                const short* __restrict__ WnHi,
                                                const short* __restrict__ WnLo,
                                                const float* __restrict__ bias,
                                                float* __restrict__ hs,
                                                __half* __restrict__ hw, int N) {
    int tid = threadIdx.x;
    int w = tid >> 6, l = tid & 63;
    int rb = blockIdx.x;
    int path = w & 1, rg = w >> 1;
    int row0 = rb * 128 + rg * 64;
    const short* BH = path ? WnHi : WsHi;
    const short* BL = path ? WnLo : WsLo;

    f32x4 acc[4][3];
#pragma unroll
    for (int i = 0; i < 4; ++i)
#pragma unroll
        for (int j = 0; j < 3; ++j) acc[i][j] = (f32x4){0.f, 0.f, 0.f, 0.f};

#pragma unroll
    for (int c = 0; c < 4; ++c) {
        bf16x8 ah[4], al[4], bh[3], bl[3];
#pragma unroll
        for (int rt = 0; rt < 4; ++rt) {
            size_t ai = (((size_t)(rb * 8 + rg * 4 + rt) * 4 + c) * 64 + l) * 8;
            ah[rt] = *(const bf16x8*)(Ah + ai);
            al[rt] = *(const bf16x8*)(Al + ai);
        }
#pragma unroll
        for (int ct = 0; ct < 3; ++ct) {
            size_t bi = (((size_t)ct * 4 + c) * 64 + l) * 8;
            bh[ct] = *(const bf16x8*)(BH + bi);
            bl[ct] = *(const bf16x8*)(BL + bi);
        }
#pragma unroll
        for (int rt = 0; rt < 4; ++rt)
#pragma unroll
            for (int ct = 0; ct < 3; ++ct) {
                acc[rt][ct] = MFMA16(ah[rt], bh[ct], acc[rt][ct]);
                acc[rt][ct] = MFMA16(ah[rt], bl[ct], acc[rt][ct]);
                acc[rt][ct] = MFMA16(al[rt], bh[ct], acc[rt][ct]);
            }
    }

    int q = l >> 4, n15 = l & 15;
#pragma unroll
    for (int ct = 0; ct < 3; ++ct) {
        int col = ct * 16 + n15;
        float b = (path == 0 && col < 47) ? bias[col] : 0.f;
#pragma unroll
        for (int rt = 0; rt < 4; ++rt) {
            int rbase = row0 + rt * 16 + q * 4;
#pragma unroll
            for (int r = 0; r < 4; ++r) {
                int row = rbase + r;
                if (row >= N) continue;
                if (path == 0) {
                    if (col < 47) hs[(size_t)row * 47 + col] = acc[rt][ct][r] + b;
                } else {
                    hw[(size_t)row * 48 + col] = __float2half(acc[rt][ct][r]);
                }
            }
        }
    }
}

// ---------------- combine (mid): 8-wide MLP gather, relu, write packed split-bf16 ------

__global__ __launch_bounds__(256) void k_combine_mid(const float* __restrict__ hs,
                                                     const __half2* __restrict__ hw,
                                                     const int* __restrict__ csr,
                                                     const int* __restrict__ offs,
                                                     const int* __restrict__ deg,
                                                     const float* __restrict__ dinv,
                                                     short* __restrict__ Ah,
                                                     short* __restrict__ Al, int N) {
    int wid = (blockIdx.x * 256 + threadIdx.x) >> 6;
    int l = threadIdx.x & 63;
    if (wid >= N) return;
    int beg = __builtin_amdgcn_readfirstlane(offs[wid]);
    int d   = __builtin_amdgcn_readfirstlane(deg[wid]);
    float acc0 = 0.f, acc1 = 0.f;
    for (int e = 0; e < d; e += 8) {
        int u[8];
#pragma unroll
        for (int i = 0; i < 8; ++i) {
            int idx = (e + i < d) ? (beg + e + i) : beg;  // clamp to valid (d>0 here)
            u[i] = csr[idx];
        }
        float2 c[8];
#pragma unroll
        for (int i = 0; i < 8; ++i) c[i] = __half22float2(hw[(size_t)u[i] * 64 + l]);
#pragma unroll
        for (int i = 0; i < 8; ++i) {
            float m = (e + i < d) ? 1.f : 0.f;
            acc0 = fmaf(m, c[i].x, acc0);
            acc1 = fmaf(m, c[i].y, acc1);
        }
    }
    float di = dinv[wid];
    float2 s = ((const float2*)hs)[(size_t)wid * 64 + l];
    float v0 = fmaxf(s.x + di * acc0, 0.f);
    float v1 = fmaxf(s.y + di * acc1, 0.f);

    int rt = wid >> 4, mm = wid & 15;
    int k0 = l * 2;
    int c4 = k0 >> 5, q = (k0 & 31) >> 3, j = k0 & 7;
    size_t idx = ((size_t)(rt * 4 + c4) * 64 + q * 16 + mm) * 8 + j;
    short h0 = f2bf(v0), h1 = f2bf(v1);
    *(short2*)(Ah + idx) = make_short2(h0, h1);
    *(short2*)(Al + idx) = make_short2(f2bf(v0 - bf2f(h0)), f2bf(v1 - bf2f(h1)));
}

// ---------------- combine (final, Fo=47): 8-wide MLP gather, fp32 out ----------------

__global__ __launch_bounds__(256) void k_combine_final(const float* __restrict__ hs,
                                                       const __half2* __restrict__ hw,
                                                       const int* __restrict__ csr,
                                                       const int* __restrict__ offs,
                                                       const int* __restrict__ deg,
                                                       const float* __restrict__ dinv,
                                                       float* __restrict__ out, int N) {
    int wid = (blockIdx.x * 256 + threadIdx.x) >> 6;
    int l = threadIdx.x & 63;
    if (wid >= N) return;
    int beg = __builtin_amdgcn_readfirstlane(offs[wid]);
    int d   = __builtin_amdgcn_readfirstlane(deg[wid]);
    if (l >= 24) return;  // 48/2 half2s
    float acc0 = 0.f, acc1 = 0.f;
    for (int e = 0; e < d; e += 8) {
        int u[8];
#pragma unroll
        for (int i = 0; i < 8; ++i) {
            int idx = (e + i < d) ? (beg + e + i) : beg;
            u[i] = csr[idx];
        }
        float2 c[8];
#pragma unroll
        for (int i = 0; i < 8; ++i) c[i] = __half22float2(hw[(size_t)u[i] * 24 + l]);
#pragma unroll
        for (int i = 0; i < 8; ++i) {
            float m = (e + i < d) ? 1.f : 0.f;
            acc0 = fmaf(m, c[i].x, acc0);
            acc1 = fmaf(m, c[i].y, acc1);
        }
    }
    float di = dinv[wid];
    int f0 = l * 2, f1 = l * 2 + 1;
    out[(size_t)wid * 47 + f0] = hs[(size_t)wid * 47 + f0] + di * acc0;
    if (f1 < 47) out[(size_t)wid * 47 + f1] = hs[(size_t)wid * 47 + f1] + di * acc1;
}

// ---------------- launch ----------------

extern "C" void kernel_launch(void* const* d_in, const int* in_sizes, int n_in,
                              void* d_out, int out_size, void* d_ws, size_t ws_size,
                              hipStream_t stream) {
    const int N = NN, E = NE;
    const float* x   = (const float*)d_in[0];
    const int*   src = (const int*)d_in[1];
    const int*   dst = (const int*)d_in[2];
    const float* Ws0 = (const float*)d_in[3];
    const float* Wn0 = (const float*)d_in[4];
    const float* b0  = (const float*)d_in[5];
    const float* Ws1 = (const float*)d_in[6];
    const float* Wn1 = (const float*)d_in[7];
    const float* b1  = (const float*)d_in[8];
    const float* Ws2 = (const float*)d_in[9];
    const float* Wn2 = (const float*)d_in[10];
    const float* b2  = (const float*)d_in[11];
    float* out = (float*)d_out;

    char* p = (char*)d_ws;
    size_t o = 0;
    auto alloc = [&](size_t bytes) -> void* {
        void* q = p + o;
        o = (o + bytes + 511) & ~(size_t)511;
        return q;
    };
    const size_t RTPAD = 6256;  // row-tiles of 16, padded to gemm47 block span
    int*    deg    = (int*)alloc((size_t)N * 4);
    int*    offs   = (int*)alloc((size_t)N * 4);
    int*    cursor = (int*)alloc((size_t)N * 4);
    float*  dinv   = (float*)alloc((size_t)N * 4);
    int*    sums   = (int*)alloc(1024 * 4);
    int*    csr    = (int*)alloc((size_t)E * 4);
    short*  Ahp    = (short*)alloc(RTPAD * 2048 * 2);
    short*  Alp    = (short*)alloc(RTPAD * 2048 * 2);
    float*  hs     = (float*)alloc((size_t)N * 128 * 4);
    __half* hw     = (__half*)alloc((size_t)N * 128 * 2);
    short*  Whi    = (short*)alloc(77824 * 2);
    short*  Wlo    = (short*)alloc(77824 * 2);

    // ---- CSR build ----
    hipMemsetAsync(deg, 0, (size_t)N * 4, stream);
    k_count<<<(E + 255) / 256, 256, 0, stream>>>(dst, deg, E);
    int nb = (N + 1023) / 1024;
    k_scan1<<<nb, 1024, 0, stream>>>(deg, offs, sums, N);
    k_scan2<<<1, 128, 0, stream>>>(sums, nb);
    k_finalize<<<(N + 255) / 256, 256, 0, stream>>>(offs, sums, deg, cursor, dinv, N);
    k_scatter<<<(E + 255) / 256, 256, 0, stream>>>(src, dst, cursor, csr, E);

    // ---- pack weights + split input ----
    k_packW<<<dim3(64, 6), 256, 0, stream>>>(Ws0, Wn0, Ws1, Wn1, Ws2, Wn2, Whi, Wlo);
    k_splitA<<<(N * 64 + 255) / 256, 256, 0, stream>>>(x, Ahp, Alp, N);

    int g128 = (N + 63) / 64;
    int g47  = (N + 127) / 128;
    int cwg  = (N * 64 + 255) / 256;

    // ---- layer 0 ----
    k_gemm128<<<g128, 256, 0, stream>>>(Ahp, Alp, Whi, Wlo, Whi + 16384, Wlo + 16384,
                                        b0, hs, hw, N);
    k_combine_mid<<<cwg, 256, 0, stream>>>(hs, (const __half2*)hw, csr, offs, deg, dinv,
                                           Ahp, Alp, N);
    // ---- layer 1 ----
    k_gemm128<<<g128, 256, 0, stream>>>(Ahp, Alp, Whi + 32768, Wlo + 32768,
                                        Whi + 49152, Wlo + 49152, b1, hs, hw, N);
    k_combine_mid<<<cwg, 256, 0, stream>>>(hs, (const __half2*)hw, csr, offs, deg, dinv,
                                           Ahp, Alp, N);
    // ---- layer 2 (Fo=47, hw padded to 48) ----
    k_gemm47<<<g47, 256, 0, stream>>>(Ahp, Alp, Whi + 65536, Wlo + 65536,
                                      Whi + 71680, Wlo + 71680, b2, hs, hw, N);
    k_combine_final<<<cwg, 256, 0, stream>>>(hs, (const __half2*)hw, csr, offs, deg, dinv,
                                             out, N);
}

// Round 5
// 565.625 us; speedup vs baseline: 2.1524x; 1.2046x over previous
//
#include <hip/hip_runtime.h>
#include <hip/hip_fp16.h>

#define NN 100000
#define NE 1600000
#define NB_BUCKETS 391   // ceil(100000 / 256); bucket = 256 consecutive dst nodes
#define EPB 8192         // edges per partition block

typedef __attribute__((ext_vector_type(8))) short bf16x8;
typedef __attribute__((ext_vector_type(4))) float f32x4;
#define MFMA16(a, b, c) __builtin_amdgcn_mfma_f32_16x16x32_bf16(a, b, c, 0, 0, 0)

__device__ __forceinline__ short f2bf(float x) {
    union { float f; unsigned u; } v; v.f = x;
    unsigned r = v.u + 0x7FFF + ((v.u >> 16) & 1);  // RN-even
    return (short)(r >> 16);
}
__device__ __forceinline__ float bf2f(short h) {
    union { float f; unsigned u; } v; v.u = ((unsigned)(unsigned short)h) << 16;
    return v.f;
}

// ================= CSR build: bucketed counting sort =================
// Buckets of 256 consecutive dst nodes. Edge packed as (dstLocal<<24)|src
// (src < 2^17). All writes land in per-bucket contiguous regions -> full
// cache lines (round-4 scatter paid 105 MB writeback for a 6.4 MB array).

__global__ __launch_bounds__(256) void k_hist(const int* __restrict__ dst,
                                              int* __restrict__ histCnt, int E) {
    __shared__ int h[NB_BUCKETS];
    for (int i = threadIdx.x; i < NB_BUCKETS; i += 256) h[i] = 0;
    __syncthreads();
    int base = blockIdx.x * EPB;
    for (int i = threadIdx.x; i < EPB; i += 256) {
        int e = base + i;
        if (e < E) atomicAdd(&h[((unsigned)dst[e]) >> 8], 1);
    }
    __syncthreads();
    for (int i = threadIdx.x; i < NB_BUCKETS; i += 256)
        if (h[i]) atomicAdd(&histCnt[i], h[i]);
}

__global__ __launch_bounds__(256) void k_scanB(const int* __restrict__ histCnt,
                                               int* __restrict__ bucketBase,
                                               int* __restrict__ bucketCursor) {
    __shared__ int s[512];
    int t = threadIdx.x;
    s[t] = (t < NB_BUCKETS) ? histCnt[t] : 0;
    s[t + 256] = (t + 256 < NB_BUCKETS) ? histCnt[t + 256] : 0;
    __syncthreads();
    for (int off = 1; off < 512; off <<= 1) {
        int v0 = (t >= off) ? s[t - off] : 0;
        int v1 = (t + 256 >= off) ? s[t + 256 - off] : 0;
        __syncthreads();
        s[t] += v0;
        s[t + 256] += v1;
        __syncthreads();
    }
    for (int i = t; i < NB_BUCKETS + 1; i += 256) {
        int base = (i == 0) ? 0 : s[i - 1];
        bucketBase[i] = base;
        if (i < NB_BUCKETS) bucketCursor[i] = base;
    }
}

__global__ __launch_bounds__(256) void k_partition(const int* __restrict__ src,
                                                   const int* __restrict__ dst,
                                                   int* __restrict__ bucketCursor,
                                                   unsigned* __restrict__ packed, int E) {
    __shared__ int h[NB_BUCKETS];
    __shared__ int cur[NB_BUCKETS];
    for (int i = threadIdx.x; i < NB_BUCKETS; i += 256) h[i] = 0;
    __syncthreads();
    int base = blockIdx.x * EPB;
    for (int i = threadIdx.x; i < EPB; i += 256) {
        int e = base + i;
        if (e < E) atomicAdd(&h[((unsigned)dst[e]) >> 8], 1);
    }
    __syncthreads();
    for (int i = threadIdx.x; i < NB_BUCKETS; i += 256)
        cur[i] = h[i] ? atomicAdd(&bucketCursor[i], h[i]) : 0;
    __syncthreads();
    for (int i = threadIdx.x; i < EPB; i += 256) {
        int e = base + i;
        if (e < E) {
            unsigned d = (unsigned)dst[e];
            unsigned b = d >> 8;
            int pos = atomicAdd(&cur[b], 1);
            packed[pos] = ((d & 255u) << 24) | (unsigned)src[e];
        }
    }
}

// One block per bucket: LDS histogram+scan gives deg/offs/dinv; scatter src
// into the bucket's contiguous csr region (L2-resident, full-line writes).
__global__ __launch_bounds__(256) void k_bucket(const unsigned* __restrict__ packed,
                                                const int* __restrict__ bucketBase,
                                                int* __restrict__ deg,
                                                int* __restrict__ offs,
                                                float* __restrict__ dinv,
                                                int* __restrict__ csr, int N) {
    __shared__ int hist[256];
    __shared__ int cur[256];
    int b = blockIdx.x, t = threadIdx.x;
    int lo = bucketBase[b], hi = bucketBase[b + 1];
    hist[t] = 0;
    __syncthreads();
    for (int i = lo + t; i < hi; i += 256)
        atomicAdd(&hist[packed[i] >> 24], 1);
    __syncthreads();
    int myDeg = hist[t];
    for (int off = 1; off < 256; off <<= 1) {  // inclusive scan
        int v = (t >= off) ? hist[t - off] : 0;
        __syncthreads();
        hist[t] += v;
        __syncthreads();
    }
    int excl = hist[t] - myDeg;
    cur[t] = lo + excl;
    int node = (b << 8) + t;
    if (node < N) {
        deg[node] = myDeg;
        offs[node] = lo + excl;
        dinv[node] = 1.0f / (float)(myDeg > 0 ? myDeg : 1);
    }
    __syncthreads();
    for (int i = lo + t; i < hi; i += 256) {
        unsigned w = packed[i];
        int pos = atomicAdd(&cur[w >> 24], 1);
        csr[pos] = (int)(w & 0x00FFFFFFu);
    }
}

// ---------------- pack W into B-fragment order, bf16 hi/lo split ----------------
// B-frag: lane l holds B[k = c*32 + (l>>4)*8 + j][n = ct*16 + (l&15)]
// packed elem index: ((ct*4 + c)*64 + lane)*8 + j

__global__ void k_packW(const float* __restrict__ W0, const float* __restrict__ W1,
                        const float* __restrict__ W2, const float* __restrict__ W3,
                        const float* __restrict__ W4, const float* __restrict__ W5,
                        short* __restrict__ Whi, short* __restrict__ Wlo) {
    int m = blockIdx.y;
    const float* W; int Fo, nct, off;
    switch (m) {
        case 0: W = W0; Fo = 128; nct = 8; off = 0;     break;
        case 1: W = W1; Fo = 128; nct = 8; off = 16384; break;
        case 2: W = W2; Fo = 128; nct = 8; off = 32768; break;
        case 3: W = W3; Fo = 128; nct = 8; off = 49152; break;
        case 4: W = W4; Fo = 47;  nct = 3; off = 65536; break;
        default:W = W5; Fo = 47;  nct = 3; off = 71680; break;
    }
    int e = blockIdx.x * 256 + threadIdx.x;
    if (e >= nct * 2048) return;
    int j = e & 7, lane = (e >> 3) & 63, c = (e >> 9) & 3, ct = e >> 11;
    int k = c * 32 + (lane >> 4) * 8 + j;
    int n = ct * 16 + (lane & 15);
    float v = (n < Fo) ? W[(size_t)k * Fo + n] : 0.f;
    short h = f2bf(v);
    Whi[off + e] = h;
    Wlo[off + e] = f2bf(v - bf2f(h));
}

// ---------------- split A (fp32 row-major) into packed bf16 hi/lo A-frag order --------

__global__ void k_splitA(const float* __restrict__ A, short* __restrict__ Ah,
                         short* __restrict__ Al, int N) {
    int t = blockIdx.x * 256 + threadIdx.x;
    if (t >= N * 64) return;
    int n = t >> 6;
    int kp = (t & 63) * 2;
    float2 v = *(const float2*)(A + (size_t)n * 128 + kp);
    int rt = n >> 4, mm = n & 15;
    int c = kp >> 5, q = (kp & 31) >> 3, j = kp & 7;
    size_t idx = ((size_t)(rt * 4 + c) * 64 + q * 16 + mm) * 8 + j;
    short h0 = f2bf(v.x), h1 = f2bf(v.y);
    *(short2*)(Ah + idx) = make_short2(h0, h1);
    *(short2*)(Al + idx) = make_short2(f2bf(v.x - bf2f(h0)), f2bf(v.y - bf2f(h1)));
}

// ---------------- MFMA dual GEMM, Fo=128 ----------------

__global__ __launch_bounds__(256) void k_gemm128(const short* __restrict__ Ah,
                                                 const short* __restrict__ Al,
                                                 const short* __restrict__ WsHi,
                                                 const short* __restrict__ WsLo,
                                                 const short* __restrict__ WnHi,
                                                 const short* __restrict__ WnLo,
                                                 const float* __restrict__ bias,
                                                 float* __restrict__ hs,
                                                 __half* __restrict__ hw, int N) {
    int tid = threadIdx.x;
    int w = tid >> 6, l = tid & 63;
    int rb = blockIdx.x, row0 = rb * 64;
    int path = w >> 1, cg = w & 1;
    const short* BH = path ? WnHi : WsHi;
    const short* BL = path ? WnLo : WsLo;

    f32x4 acc[4][4];
#pragma unroll
    for (int i = 0; i < 4; ++i)
#pragma unroll
        for (int j = 0; j < 4; ++j) acc[i][j] = (f32x4){0.f, 0.f, 0.f, 0.f};

#pragma unroll
    for (int c = 0; c < 4; ++c) {
        bf16x8 ah[4], al[4], bh[4], bl[4];
#pragma unroll
        for (int rt = 0; rt < 4; ++rt) {
            size_t ai = (((size_t)(rb * 4 + rt) * 4 + c) * 64 + l) * 8;
            ah[rt] = *(const bf16x8*)(Ah + ai);
            al[rt] = *(const bf16x8*)(Al + ai);
        }
#pragma unroll
        for (int ct = 0; ct < 4; ++ct) {
            size_t bi = (((size_t)(cg * 4 + ct) * 4 + c) * 64 + l) * 8;
            bh[ct] = *(const bf16x8*)(BH + bi);
            bl[ct] = *(const bf16x8*)(BL + bi);
        }
#pragma unroll
        for (int rt = 0; rt < 4; ++rt)
#pragma unroll
            for (int ct = 0; ct < 4; ++ct) {
                acc[rt][ct] = MFMA16(ah[rt], bh[ct], acc[rt][ct]);
                acc[rt][ct] = MFMA16(ah[rt], bl[ct], acc[rt][ct]);
                acc[rt][ct] = MFMA16(al[rt], bh[ct], acc[rt][ct]);
            }
    }

    // C/D layout: col = l&15, row = (l>>4)*4 + r   [verified m89/m91]
    int q = l >> 4, n15 = l & 15;
#pragma unroll
    for (int ct = 0; ct < 4; ++ct) {
        int col = (cg * 4 + ct) * 16 + n15;
        float b = (path == 0) ? bias[col] : 0.f;
#pragma unroll
        for (int rt = 0; rt < 4; ++rt) {
            int rbase = row0 + rt * 16 + q * 4;
#pragma unroll
            for (int r = 0; r < 4; ++r) {
                int row = rbase + r;
                if (row >= N) continue;
                if (path == 0)
                    hs[(size_t)row * 128 + col] = acc[rt][ct][r] + b;
                else
                    hw[(size_t)row * 128 + col] = __float2half(acc[rt][ct][r]);
            }
        }
    }
}

// ---------------- MFMA dual GEMM, Fo=47 (padded 48) ----------------

__global__ __launch_bounds__(256) void k_gemm47(const short* __restrict__ Ah,
                                                const short* __restrict__ Al,
                                                const short* __restrict__ WsHi,
                                                const short* __restrict__ WsLo,
                                                const short* __restrict__ WnHi,
                                                const short* __restrict__ WnLo,
                                                const float* __restrict__ bias,
                                                float* __restrict__ hs,
                                                __half* __restrict__ hw, int N) {
    int tid = threadIdx.x;
    int w = tid >> 6, l = tid & 63;
    int rb = blockIdx.x;
    int path = w & 1, rg = w >> 1;
    int row0 = rb * 128 + rg * 64;
    const short* BH = path ? WnHi : WsHi;
    const short* BL = path ? WnLo : WsLo;

    f32x4 acc[4][3];
#pragma unroll
    for (int i = 0; i < 4; ++i)
#pragma unroll
        for (int j = 0; j < 3; ++j) acc[i][j] = (f32x4){0.f, 0.f, 0.f, 0.f};

#pragma unroll
    for (int c = 0; c < 4; ++c) {
        bf16x8 ah[4], al[4], bh[3], bl[3];
#pragma unroll
        for (int rt = 0; rt < 4; ++rt) {
            size_t ai = (((size_t)(rb * 8 + rg * 4 + rt) * 4 + c) * 64 + l) * 8;
            ah[rt] = *(const bf16x8*)(Ah + ai);
            al[rt] = *(const bf16x8*)(Al + ai);
        }
#pragma unroll
        for (int ct = 0; ct < 3; ++ct) {
            size_t bi = (((size_t)ct * 4 + c) * 64 + l) * 8;
            bh[ct] = *(const bf16x8*)(BH + bi);
            bl[ct] = *(const bf16x8*)(BL + bi);
        }
#pragma unroll
        for (int rt = 0; rt < 4; ++rt)
#pragma unroll
            for (int ct = 0; ct < 3; ++ct) {
                acc[rt][ct] = MFMA16(ah[rt], bh[ct], acc[rt][ct]);
                acc[rt][ct] = MFMA16(ah[rt], bl[ct], acc[rt][ct]);
                acc[rt][ct] = MFMA16(al[rt], bh[ct], acc[rt][ct]);
            }
    }

    int q = l >> 4, n15 = l & 15;
#pragma unroll
    for (int ct = 0; ct < 3; ++ct) {
        int col = ct * 16 + n15;
        float b = (path == 0 && col < 47) ? bias[col] : 0.f;
#pragma unroll
        for (int rt = 0; rt < 4; ++rt) {
            int rbase = row0 + rt * 16 + q * 4;
#pragma unroll
            for (int r = 0; r < 4; ++r) {
                int row = rbase + r;
                if (row >= N) continue;
                if (path == 0) {
                    if (col < 47) hs[(size_t)row * 47 + col] = acc[rt][ct][r] + b;
                } else {
                    hw[(size_t)row * 48 + col] = __float2half(acc[rt][ct][r]);
                }
            }
        }
    }
}

// ---------------- combine (mid): 8-wide MLP gather, relu, write packed split-bf16 ------

__global__ __launch_bounds__(256) void k_combine_mid(const float* __restrict__ hs,
                                                     const __half2* __restrict__ hw,
                                                     const int* __restrict__ csr,
                                                     const int* __restrict__ offs,
                                                     const int* __restrict__ deg,
                                                     const float* __restrict__ dinv,
                                                     short* __restrict__ Ah,
                                                     short* __restrict__ Al, int N) {
    int wid = (blockIdx.x * 256 + threadIdx.x) >> 6;
    int l = threadIdx.x & 63;
    if (wid >= N) return;
    int beg = __builtin_amdgcn_readfirstlane(offs[wid]);
    int d   = __builtin_amdgcn_readfirstlane(deg[wid]);
    float acc0 = 0.f, acc1 = 0.f;
    for (int e = 0; e < d; e += 8) {
        int u[8];
#pragma unroll
        for (int i = 0; i < 8; ++i) {
            int idx = (e + i < d) ? (beg + e + i) : beg;  // clamp to valid (d>0 here)
            u[i] = csr[idx];
        }
        float2 c[8];
#pragma unroll
        for (int i = 0; i < 8; ++i) c[i] = __half22float2(hw[(size_t)u[i] * 64 + l]);
#pragma unroll
        for (int i = 0; i < 8; ++i) {
            float m = (e + i < d) ? 1.f : 0.f;
            acc0 = fmaf(m, c[i].x, acc0);
            acc1 = fmaf(m, c[i].y, acc1);
        }
    }
    float di = dinv[wid];
    float2 s = ((const float2*)hs)[(size_t)wid * 64 + l];
    float v0 = fmaxf(s.x + di * acc0, 0.f);
    float v1 = fmaxf(s.y + di * acc1, 0.f);

    int rt = wid >> 4, mm = wid & 15;
    int k0 = l * 2;
    int c4 = k0 >> 5, q = (k0 & 31) >> 3, j = k0 & 7;
    size_t idx = ((size_t)(rt * 4 + c4) * 64 + q * 16 + mm) * 8 + j;
    short h0 = f2bf(v0), h1 = f2bf(v1);
    *(short2*)(Ah + idx) = make_short2(h0, h1);
    *(short2*)(Al + idx) = make_short2(f2bf(v0 - bf2f(h0)), f2bf(v1 - bf2f(h1)));
}

// ---------------- combine (final, Fo=47): 8-wide MLP gather, fp32 out ----------------

__global__ __launch_bounds__(256) void k_combine_final(const float* __restrict__ hs,
                                                       const __half2* __restrict__ hw,
                                                       const int* __restrict__ csr,
                                                       const int* __restrict__ offs,
                                                       const int* __restrict__ deg,
                                                       const float* __restrict__ dinv,
                                                       float* __restrict__ out, int N) {
    int wid = (blockIdx.x * 256 + threadIdx.x) >> 6;
    int l = threadIdx.x & 63;
    if (wid >= N) return;
    int beg = __builtin_amdgcn_readfirstlane(offs[wid]);
    int d   = __builtin_amdgcn_readfirstlane(deg[wid]);
    if (l >= 24) return;  // 48/2 half2s
    float acc0 = 0.f, acc1 = 0.f;
    for (int e = 0; e < d; e += 8) {
        int u[8];
#pragma unroll
        for (int i = 0; i < 8; ++i) {
            int idx = (e + i < d) ? (beg + e + i) : beg;
            u[i] = csr[idx];
        }
        float2 c[8];
#pragma unroll
        for (int i = 0; i < 8; ++i) c[i] = __half22float2(hw[(size_t)u[i] * 24 + l]);
#pragma unroll
        for (int i = 0; i < 8; ++i) {
            float m = (e + i < d) ? 1.f : 0.f;
            acc0 = fmaf(m, c[i].x, acc0);
            acc1 = fmaf(m, c[i].y, acc1);
        }
    }
    float di = dinv[wid];
    int f0 = l * 2, f1 = l * 2 + 1;
    out[(size_t)wid * 47 + f0] = hs[(size_t)wid * 47 + f0] + di * acc0;
    if (f1 < 47) out[(size_t)wid * 47 + f1] = hs[(size_t)wid * 47 + f1] + di * acc1;
}

// ---------------- launch ----------------

extern "C" void kernel_launch(void* const* d_in, const int* in_sizes, int n_in,
                              void* d_out, int out_size, void* d_ws, size_t ws_size,
                              hipStream_t stream) {
    const int N = NN, E = NE;
    const float* x   = (const float*)d_in[0];
    const int*   src = (const int*)d_in[1];
    const int*   dst = (const int*)d_in[2];
    const float* Ws0 = (const float*)d_in[3];
    const float* Wn0 = (const float*)d_in[4];
    const float* b0  = (const float*)d_in[5];
    const float* Ws1 = (const float*)d_in[6];
    const float* Wn1 = (const float*)d_in[7];
    const float* b1  = (const float*)d_in[8];
    const float* Ws2 = (const float*)d_in[9];
    const float* Wn2 = (const float*)d_in[10];
    const float* b2  = (const float*)d_in[11];
    float* out = (float*)d_out;

    char* p = (char*)d_ws;
    size_t o = 0;
    auto alloc = [&](size_t bytes) -> void* {
        void* q = p + o;
        o = (o + bytes + 511) & ~(size_t)511;
        return q;
    };
    const size_t RTPAD = 6256;  // row-tiles of 16, padded to gemm47 block span
    int*      deg     = (int*)alloc((size_t)N * 4);
    int*      offs    = (int*)alloc((size_t)N * 4);
    float*    dinv    = (float*)alloc((size_t)N * 4);
    int*      histCnt = (int*)alloc(NB_BUCKETS * 4);
    int*      bBase   = (int*)alloc((NB_BUCKETS + 1) * 4);
    int*      bCur    = (int*)alloc(NB_BUCKETS * 4);
    unsigned* packed  = (unsigned*)alloc((size_t)E * 4);
    int*      csr     = (int*)alloc((size_t)E * 4);
    short*    Ahp     = (short*)alloc(RTPAD * 2048 * 2);
    short*    Alp     = (short*)alloc(RTPAD * 2048 * 2);
    float*    hs      = (float*)alloc((size_t)N * 128 * 4);
    __half*   hw      = (__half*)alloc((size_t)N * 128 * 2);
    short*    Whi     = (short*)alloc(77824 * 2);
    short*    Wlo     = (short*)alloc(77824 * 2);

    // ---- CSR build: hist -> scan -> partition -> per-bucket sort ----
    hipMemsetAsync(histCnt, 0, NB_BUCKETS * 4, stream);
    int pgrid = (E + EPB - 1) / EPB;  // 196
    k_hist<<<pgrid, 256, 0, stream>>>(dst, histCnt, E);
    k_scanB<<<1, 256, 0, stream>>>(histCnt, bBase, bCur);
    k_partition<<<pgrid, 256, 0, stream>>>(src, dst, bCur, packed, E);
    k_bucket<<<NB_BUCKETS, 256, 0, stream>>>(packed, bBase, deg, offs, dinv, csr, N);

    // ---- pack weights + split input ----
    k_packW<<<dim3(64, 6), 256, 0, stream>>>(Ws0, Wn0, Ws1, Wn1, Ws2, Wn2, Whi, Wlo);
    k_splitA<<<(N * 64 + 255) / 256, 256, 0, stream>>>(x, Ahp, Alp, N);

    int g128 = (N + 63) / 64;
    int g47  = (N + 127) / 128;
    int cwg  = (N * 64 + 255) / 256;

    // ---- layer 0 ----
    k_gemm128<<<g128, 256, 0, stream>>>(Ahp, Alp, Whi, Wlo, Whi + 16384, Wlo + 16384,
                                        b0, hs, hw, N);
    k_combine_mid<<<cwg, 256, 0, stream>>>(hs, (const __half2*)hw, csr, offs, deg, dinv,
                                           Ahp, Alp, N);
    // ---- layer 1 ----
    k_gemm128<<<g128, 256, 0, stream>>>(Ahp, Alp, Whi + 32768, Wlo + 32768,
                                        Whi + 49152, Wlo + 49152, b1, hs, hw, N);
    k_combine_mid<<<cwg, 256, 0, stream>>>(hs, (const __half2*)hw, csr, offs, deg, dinv,
                                           Ahp, Alp, N);
    // ---- layer 2 (Fo=47, hw padded to 48) ----
    k_gemm47<<<g47, 256, 0, stream>>>(Ahp, Alp, Whi + 65536, Wlo + 65536,
                                      Whi + 71680, Wlo + 71680, b2, hs, hw, N);
    k_combine_final<<<cwg, 256, 0, stream>>>(hs, (const __half2*)hw, csr, offs, deg, dinv,
                                             out, N);
}

// Round 6
// 439.494 us; speedup vs baseline: 2.7702x; 1.2870x over previous
//
#include <hip/hip_runtime.h>
#include <hip/hip_fp16.h>

#define NN 100000
#define NE 1600000
#define NB_BUCKETS 391   // ceil(100000 / 256); bucket = 256 consecutive dst nodes
#define EPB 8192         // edges per partition block

typedef __attribute__((ext_vector_type(8))) _Float16 f16x8;
typedef __attribute__((ext_vector_type(2))) _Float16 f16x2;
typedef __attribute__((ext_vector_type(4))) float f32x4;
#define MFMAH(a, b, c) __builtin_amdgcn_mfma_f32_16x16x32_f16(a, b, c, 0, 0, 0)

// ================= CSR build: bucketed counting sort =================

__global__ __launch_bounds__(256) void k_hist(const int* __restrict__ dst,
                                              int* __restrict__ histCnt, int E) {
    __shared__ int h[NB_BUCKETS];
    for (int i = threadIdx.x; i < NB_BUCKETS; i += 256) h[i] = 0;
    __syncthreads();
    int base = blockIdx.x * EPB;
    for (int i = threadIdx.x; i < EPB; i += 256) {
        int e = base + i;
        if (e < E) atomicAdd(&h[((unsigned)dst[e]) >> 8], 1);
    }
    __syncthreads();
    for (int i = threadIdx.x; i < NB_BUCKETS; i += 256)
        if (h[i]) atomicAdd(&histCnt[i], h[i]);
}

__global__ __launch_bounds__(256) void k_scanB(const int* __restrict__ histCnt,
                                               int* __restrict__ bucketBase,
                                               int* __restrict__ bucketCursor) {
    __shared__ int s[512];
    int t = threadIdx.x;
    s[t] = (t < NB_BUCKETS) ? histCnt[t] : 0;
    s[t + 256] = (t + 256 < NB_BUCKETS) ? histCnt[t + 256] : 0;
    __syncthreads();
    for (int off = 1; off < 512; off <<= 1) {
        int v0 = (t >= off) ? s[t - off] : 0;
        int v1 = (t + 256 >= off) ? s[t + 256 - off] : 0;
        __syncthreads();
        s[t] += v0;
        s[t + 256] += v1;
        __syncthreads();
    }
    for (int i = t; i < NB_BUCKETS + 1; i += 256) {
        int base = (i == 0) ? 0 : s[i - 1];
        bucketBase[i] = base;
        if (i < NB_BUCKETS) bucketCursor[i] = base;
    }
}

__global__ __launch_bounds__(256) void k_partition(const int* __restrict__ src,
                                                   const int* __restrict__ dst,
                                                   int* __restrict__ bucketCursor,
                                                   unsigned* __restrict__ packed, int E) {
    __shared__ int h[NB_BUCKETS];
    __shared__ int cur[NB_BUCKETS];
    for (int i = threadIdx.x; i < NB_BUCKETS; i += 256) h[i] = 0;
    __syncthreads();
    int base = blockIdx.x * EPB;
    for (int i = threadIdx.x; i < EPB; i += 256) {
        int e = base + i;
        if (e < E) atomicAdd(&h[((unsigned)dst[e]) >> 8], 1);
    }
    __syncthreads();
    for (int i = threadIdx.x; i < NB_BUCKETS; i += 256)
        cur[i] = h[i] ? atomicAdd(&bucketCursor[i], h[i]) : 0;
    __syncthreads();
    for (int i = threadIdx.x; i < EPB; i += 256) {
        int e = base + i;
        if (e < E) {
            unsigned d = (unsigned)dst[e];
            unsigned b = d >> 8;
            int pos = atomicAdd(&cur[b], 1);
            packed[pos] = ((d & 255u) << 24) | (unsigned)src[e];
        }
    }
}

__global__ __launch_bounds__(256) void k_bucket(const unsigned* __restrict__ packed,
                                                const int* __restrict__ bucketBase,
                                                int* __restrict__ deg,
                                                int* __restrict__ offs,
                                                float* __restrict__ dinv,
                                                int* __restrict__ csr, int N) {
    __shared__ int hist[256];
    __shared__ int cur[256];
    int b = blockIdx.x, t = threadIdx.x;
    int lo = bucketBase[b], hi = bucketBase[b + 1];
    hist[t] = 0;
    __syncthreads();
    for (int i = lo + t; i < hi; i += 256)
        atomicAdd(&hist[packed[i] >> 24], 1);
    __syncthreads();
    int myDeg = hist[t];
    for (int off = 1; off < 256; off <<= 1) {
        int v = (t >= off) ? hist[t - off] : 0;
        __syncthreads();
        hist[t] += v;
        __syncthreads();
    }
    int excl = hist[t] - myDeg;
    cur[t] = lo + excl;
    int node = (b << 8) + t;
    if (node < N) {
        deg[node] = myDeg;
        offs[node] = lo + excl;
        dinv[node] = 1.0f / (float)(myDeg > 0 ? myDeg : 1);
    }
    __syncthreads();
    for (int i = lo + t; i < hi; i += 256) {
        unsigned w = packed[i];
        int pos = atomicAdd(&cur[w >> 24], 1);
        csr[pos] = (int)(w & 0x00FFFFFFu);
    }
}

// ---------------- pack W into B-fragment order, fp16 hi + fp16 residual ----------------
// B-frag: lane l holds B[k = c*32 + (l>>4)*8 + j][n = ct*16 + (l&15)]
// packed elem index: ((ct*4 + c)*64 + lane)*8 + j
// W = hi + lo exactly to ~2^-23 relative -> GEMM error comes only from fp16 A.

__global__ void k_packW(const float* __restrict__ W0, const float* __restrict__ W1,
                        const float* __restrict__ W2, const float* __restrict__ W3,
                        const float* __restrict__ W4, const float* __restrict__ W5,
                        _Float16* __restrict__ Whi, _Float16* __restrict__ Wlo) {
    int m = blockIdx.y;
    const float* W; int Fo, nct, off;
    switch (m) {
        case 0: W = W0; Fo = 128; nct = 8; off = 0;     break;
        case 1: W = W1; Fo = 128; nct = 8; off = 16384; break;
        case 2: W = W2; Fo = 128; nct = 8; off = 32768; break;
        case 3: W = W3; Fo = 128; nct = 8; off = 49152; break;
        case 4: W = W4; Fo = 47;  nct = 3; off = 65536; break;
        default:W = W5; Fo = 47;  nct = 3; off = 71680; break;
    }
    int e = blockIdx.x * 256 + threadIdx.x;
    if (e >= nct * 2048) return;
    int j = e & 7, lane = (e >> 3) & 63, c = (e >> 9) & 3, ct = e >> 11;
    int k = c * 32 + (lane >> 4) * 8 + j;
    int n = ct * 16 + (lane & 15);
    float v = (n < Fo) ? W[(size_t)k * Fo + n] : 0.f;
    _Float16 h = (_Float16)v;
    Whi[off + e] = h;
    Wlo[off + e] = (_Float16)(v - (float)h);
}

// ---------------- cast x (fp32 row-major) into packed fp16 A-frag order ----------------
// A-frag: lane l holds A[rowtile*16 + (l&15)][c*32 + (l>>4)*8 + j]
// packed elem index: ((rowtile*4 + c)*64 + lane)*8 + j

__global__ void k_castA(const float* __restrict__ A, _Float16* __restrict__ Ap, int N) {
    int t = blockIdx.x * 256 + threadIdx.x;
    if (t >= N * 64) return;
    int n = t >> 6;
    int kp = (t & 63) * 2;
    float2 v = *(const float2*)(A + (size_t)n * 128 + kp);
    int rt = n >> 4, mm = n & 15;
    int c = kp >> 5, q = (kp & 31) >> 3, j = kp & 7;
    size_t idx = ((size_t)(rt * 4 + c) * 64 + q * 16 + mm) * 8 + j;
    *(f16x2*)(Ap + idx) = (f16x2){(_Float16)v.x, (_Float16)v.y};
}

// ---------------- MFMA dual GEMM, Fo=128 ----------------
// Block: 256 thr = 4 waves, 32 rows/block (N%32==0 -> no row guard).
// Wave: path = w>>1 (0 self, 1 neigh), col half cg = w&1; 2 rowtiles x 4 coltiles,
// 2 MFMAs per tile (A_fp16 * Whi + A_fp16 * Wlo). acc = 8 f32x4 = 32 AGPRs.

__global__ __launch_bounds__(256) void k_gemm128(const _Float16* __restrict__ Ap,
                                                 const _Float16* __restrict__ WsHi,
                                                 const _Float16* __restrict__ WsLo,
                                                 const _Float16* __restrict__ WnHi,
                                                 const _Float16* __restrict__ WnLo,
                                                 const float* __restrict__ bias,
                                                 _Float16* __restrict__ hs,
                                                 _Float16* __restrict__ hw, int N) {
    int tid = threadIdx.x;
    int w = tid >> 6, l = tid & 63;
    int rb = blockIdx.x;
    int path = w >> 1, cg = w & 1;
    const _Float16* BH = path ? WnHi : WsHi;
    const _Float16* BL = path ? WnLo : WsLo;

    f32x4 acc[2][4];
#pragma unroll
    for (int i = 0; i < 2; ++i)
#pragma unroll
        for (int j = 0; j < 4; ++j) acc[i][j] = (f32x4){0.f, 0.f, 0.f, 0.f};

#pragma unroll
    for (int c = 0; c < 4; ++c) {
        f16x8 a[2], bh[4], bl[4];
#pragma unroll
        for (int rt = 0; rt < 2; ++rt) {
            size_t ai = (((size_t)(rb * 2 + rt) * 4 + c) * 64 + l) * 8;
            a[rt] = *(const f16x8*)(Ap + ai);
        }
#pragma unroll
        for (int ct = 0; ct < 4; ++ct) {
            size_t bi = (((size_t)(cg * 4 + ct) * 4 + c) * 64 + l) * 8;
            bh[ct] = *(const f16x8*)(BH + bi);
            bl[ct] = *(const f16x8*)(BL + bi);
        }
#pragma unroll
        for (int rt = 0; rt < 2; ++rt)
#pragma unroll
            for (int ct = 0; ct < 4; ++ct) {
                acc[rt][ct] = MFMAH(a[rt], bh[ct], acc[rt][ct]);
                acc[rt][ct] = MFMAH(a[rt], bl[ct], acc[rt][ct]);
            }
    }

    // C/D layout: col = l&15, row = (l>>4)*4 + r   [verified m89/m91]
    int q = l >> 4, n15 = l & 15;
#pragma unroll
    for (int ct = 0; ct < 4; ++ct) {
        int col = (cg * 4 + ct) * 16 + n15;
        float b = (path == 0) ? bias[col] : 0.f;
#pragma unroll
        for (int rt = 0; rt < 2; ++rt) {
            int rbase = rb * 32 + rt * 16 + q * 4;
#pragma unroll
            for (int r = 0; r < 4; ++r) {
                int row = rbase + r;
                if (path == 0)
                    hs[(size_t)row * 128 + col] = (_Float16)(acc[rt][ct][r] + b);
                else
                    hw[(size_t)row * 128 + col] = (_Float16)acc[rt][ct][r];
            }
        }
    }
}

// ---------------- MFMA dual GEMM, Fo=47 (padded 48; col 47 computes to 0) ----------------
// Block: 64 rows, 4 waves: path = w&1, row half rh = w>>1. 2 rowtiles x 3 coltiles.

__global__ __launch_bounds__(256) void k_gemm47(const _Float16* __restrict__ Ap,
                                                const _Float16* __restrict__ WsHi,
                                                const _Float16* __restrict__ WsLo,
                                                const _Float16* __restrict__ WnHi,
                                                const _Float16* __restrict__ WnLo,
                                                const float* __restrict__ bias,
                                                _Float16* __restrict__ hs48,
                                                _Float16* __restrict__ hw48, int N) {
    int tid = threadIdx.x;
    int w = tid >> 6, l = tid & 63;
    int rb = blockIdx.x;
    int path = w & 1, rh = w >> 1;
    const _Float16* BH = path ? WnHi : WsHi;
    const _Float16* BL = path ? WnLo : WsLo;

    f32x4 acc[2][3];
#pragma unroll
    for (int i = 0; i < 2; ++i)
#pragma unroll
        for (int j = 0; j < 3; ++j) acc[i][j] = (f32x4){0.f, 0.f, 0.f, 0.f};

#pragma unroll
    for (int c = 0; c < 4; ++c) {
        f16x8 a[2], bh[3], bl[3];
#pragma unroll
        for (int rt = 0; rt < 2; ++rt) {
            size_t ai = (((size_t)(rb * 4 + rh * 2 + rt) * 4 + c) * 64 + l) * 8;
            a[rt] = *(const f16x8*)(Ap + ai);
        }
#pragma unroll
        for (int ct = 0; ct < 3; ++ct) {
            size_t bi = (((size_t)ct * 4 + c) * 64 + l) * 8;
            bh[ct] = *(const f16x8*)(BH + bi);
            bl[ct] = *(const f16x8*)(BL + bi);
        }
#pragma unroll
        for (int rt = 0; rt < 2; ++rt)
#pragma unroll
            for (int ct = 0; ct < 3; ++ct) {
                acc[rt][ct] = MFMAH(a[rt], bh[ct], acc[rt][ct]);
                acc[rt][ct] = MFMAH(a[rt], bl[ct], acc[rt][ct]);
            }
    }

    int q = l >> 4, n15 = l & 15;
#pragma unroll
    for (int ct = 0; ct < 3; ++ct) {
        int col = ct * 16 + n15;
        float b = (path == 0 && col < 47) ? bias[col] : 0.f;
#pragma unroll
        for (int rt = 0; rt < 2; ++rt) {
            int rbase = rb * 64 + rh * 32 + rt * 16 + q * 4;
#pragma unroll
            for (int r = 0; r < 4; ++r) {
                int row = rbase + r;
                if (row >= N) continue;
                if (path == 0)
                    hs48[(size_t)row * 48 + col] = (_Float16)(acc[rt][ct][r] + b);
                else
                    hw48[(size_t)row * 48 + col] = (_Float16)acc[rt][ct][r];
            }
        }
    }
}

// ---------------- combine (mid): 8-wide MLP gather, relu, write packed fp16 A ----------

__global__ __launch_bounds__(256) void k_combine_mid(const __half2* __restrict__ hs,
                                                     const __half2* __restrict__ hw,
                                                     const int* __restrict__ csr,
                                                     const int* __restrict__ offs,
                                                     const int* __restrict__ deg,
                                                     const float* __restrict__ dinv,
                                                     __half* __restrict__ Ap, int N) {
    int wid = (blockIdx.x * 256 + threadIdx.x) >> 6;
    int l = threadIdx.x & 63;
    if (wid >= N) return;
    int beg = __builtin_amdgcn_readfirstlane(offs[wid]);
    int d   = __builtin_amdgcn_readfirstlane(deg[wid]);
    float acc0 = 0.f, acc1 = 0.f;
    for (int e = 0; e < d; e += 8) {
        int u[8];
#pragma unroll
        for (int i = 0; i < 8; ++i) {
            int idx = (e + i < d) ? (beg + e + i) : beg;  // clamp to valid (d>0 here)
            u[i] = csr[idx];
        }
        float2 c[8];
#pragma unroll
        for (int i = 0; i < 8; ++i) c[i] = __half22float2(hw[(size_t)u[i] * 64 + l]);
#pragma unroll
        for (int i = 0; i < 8; ++i) {
            float m = (e + i < d) ? 1.f : 0.f;
            acc0 = fmaf(m, c[i].x, acc0);
            acc1 = fmaf(m, c[i].y, acc1);
        }
    }
    float di = dinv[wid];
    float2 s = __half22float2(hs[(size_t)wid * 64 + l]);
    float v0 = fmaxf(s.x + di * acc0, 0.f);
    float v1 = fmaxf(s.y + di * acc1, 0.f);

    int rt = wid >> 4, mm = wid & 15;
    int k0 = l * 2;
    int c4 = k0 >> 5, q = (k0 & 31) >> 3, j = k0 & 7;
    size_t idx = ((size_t)(rt * 4 + c4) * 64 + q * 16 + mm) * 8 + j;
    *(__half2*)(Ap + idx) = __floats2half2_rn(v0, v1);
}

// ---------------- combine (final, Fo=47): 8-wide MLP gather, fp32 out ----------------

__global__ __launch_bounds__(256) void k_combine_final(const __half2* __restrict__ hs48,
                                                       const __half2* __restrict__ hw48,
                                                       const int* __restrict__ csr,
                                                       const int* __restrict__ offs,
                                                       const int* __restrict__ deg,
                                                       const float* __restrict__ dinv,
                                                       float* __restrict__ out, int N) {
    int wid = (blockIdx.x * 256 + threadIdx.x) >> 6;
    int l = threadIdx.x & 63;
    if (wid >= N) return;
    int beg = __builtin_amdgcn_readfirstlane(offs[wid]);
    int d   = __builtin_amdgcn_readfirstlane(deg[wid]);
    if (l >= 24) return;  // 48/2 half2s
    float acc0 = 0.f, acc1 = 0.f;
    for (int e = 0; e < d; e += 8) {
        int u[8];
#pragma unroll
        for (int i = 0; i < 8; ++i) {
            int idx = (e + i < d) ? (beg + e + i) : beg;
            u[i] = csr[idx];
        }
        float2 c[8];
#pragma unroll
        for (int i = 0; i < 8; ++i) c[i] = __half22float2(hw48[(size_t)u[i] * 24 + l]);
#pragma unroll
        for (int i = 0; i < 8; ++i) {
            float m = (e + i < d) ? 1.f : 0.f;
            acc0 = fmaf(m, c[i].x, acc0);
            acc1 = fmaf(m, c[i].y, acc1);
        }
    }
    float di = dinv[wid];
    float2 s = __half22float2(hs48[(size_t)wid * 24 + l]);
    int f0 = l * 2, f1 = l * 2 + 1;
    out[(size_t)wid * 47 + f0] = s.x + di * acc0;
    if (f1 < 47) out[(size_t)wid * 47 + f1] = s.y + di * acc1;
}

// ---------------- launch ----------------

extern "C" void kernel_launch(void* const* d_in, const int* in_sizes, int n_in,
                              void* d_out, int out_size, void* d_ws, size_t ws_size,
                              hipStream_t stream) {
    const int N = NN, E = NE;
    const float* x   = (const float*)d_in[0];
    const int*   src = (const int*)d_in[1];
    const int*   dst = (const int*)d_in[2];
    const float* Ws0 = (const float*)d_in[3];
    const float* Wn0 = (const float*)d_in[4];
    const float* b0  = (const float*)d_in[5];
    const float* Ws1 = (const float*)d_in[6];
    const float* Wn1 = (const float*)d_in[7];
    const float* b1  = (const float*)d_in[8];
    const float* Ws2 = (const float*)d_in[9];
    const float* Wn2 = (const float*)d_in[10];
    const float* b2  = (const float*)d_in[11];
    float* out = (float*)d_out;

    char* p = (char*)d_ws;
    size_t o = 0;
    auto alloc = [&](size_t bytes) -> void* {
        void* q = p + o;
        o = (o + bytes + 511) & ~(size_t)511;
        return q;
    };
    const size_t RTPAD = 6252;  // rowtiles of 16: 6250 used + pad to gemm47 block span
    int*      deg     = (int*)alloc((size_t)N * 4);
    int*      offs    = (int*)alloc((size_t)N * 4);
    float*    dinv    = (float*)alloc((size_t)N * 4);
    int*      histCnt = (int*)alloc(NB_BUCKETS * 4);
    int*      bBase   = (int*)alloc((NB_BUCKETS + 1) * 4);
    int*      bCur    = (int*)alloc(NB_BUCKETS * 4);
    unsigned* packed  = (unsigned*)alloc((size_t)E * 4);
    int*      csr     = (int*)alloc((size_t)E * 4);
    _Float16* Ahp     = (_Float16*)alloc(RTPAD * 2048 * 2);
    _Float16* hs      = (_Float16*)alloc((size_t)N * 128 * 2);
    _Float16* hw      = (_Float16*)alloc((size_t)N * 128 * 2);
    _Float16* Whi     = (_Float16*)alloc(77824 * 2);
    _Float16* Wlo     = (_Float16*)alloc(77824 * 2);

    // ---- CSR build: hist -> scan -> partition -> per-bucket sort ----
    hipMemsetAsync(histCnt, 0, NB_BUCKETS * 4, stream);
    int pgrid = (E + EPB - 1) / EPB;  // 196
    k_hist<<<pgrid, 256, 0, stream>>>(dst, histCnt, E);
    k_scanB<<<1, 256, 0, stream>>>(histCnt, bBase, bCur);
    k_partition<<<pgrid, 256, 0, stream>>>(src, dst, bCur, packed, E);
    k_bucket<<<NB_BUCKETS, 256, 0, stream>>>(packed, bBase, deg, offs, dinv, csr, N);

    // ---- pack weights + cast input ----
    k_packW<<<dim3(64, 6), 256, 0, stream>>>(Ws0, Wn0, Ws1, Wn1, Ws2, Wn2, Whi, Wlo);
    k_castA<<<(N * 64 + 255) / 256, 256, 0, stream>>>(x, Ahp, N);

    int g128 = N / 32;           // 3125 (N % 32 == 0)
    int g47  = (N + 63) / 64;    // 1563
    int cwg  = (N * 64 + 255) / 256;

    // ---- layer 0 ----
    k_gemm128<<<g128, 256, 0, stream>>>(Ahp, Whi, Wlo, Whi + 16384, Wlo + 16384,
                                        b0, hs, hw, N);
    k_combine_mid<<<cwg, 256, 0, stream>>>((const __half2*)hs, (const __half2*)hw, csr,
                                           offs, deg, dinv, (__half*)Ahp, N);
    // ---- layer 1 ----
    k_gemm128<<<g128, 256, 0, stream>>>(Ahp, Whi + 32768, Wlo + 32768,
                                        Whi + 49152, Wlo + 49152, b1, hs, hw, N);
    k_combine_mid<<<cwg, 256, 0, stream>>>((const __half2*)hs, (const __half2*)hw, csr,
                                           offs, deg, dinv, (__half*)Ahp, N);
    // ---- layer 2 (Fo=47, padded 48) ----
    k_gemm47<<<g47, 256, 0, stream>>>(Ahp, Whi + 65536, Wlo + 65536,
                                      Whi + 71680, Wlo + 71680, b2, hs, hw, N);
    k_combine_final<<<cwg, 256, 0, stream>>>((const __half2*)hs, (const __half2*)hw, csr,
                                             offs, deg, dinv, out, N);
}

// Round 7
// 422.252 us; speedup vs baseline: 2.8833x; 1.0408x over previous
//
#include <hip/hip_runtime.h>
#include <hip/hip_fp16.h>

#define NN 100000
#define NE 1600000
#define NB_BUCKETS 391   // ceil(100000 / 256); bucket = 256 consecutive dst nodes
#define EPB 8192         // edges per partition block

typedef __attribute__((ext_vector_type(8))) _Float16 f16x8;
typedef __attribute__((ext_vector_type(2))) _Float16 f16x2;
typedef __attribute__((ext_vector_type(4))) float f32x4;
#define MFMAH(a, b, c) __builtin_amdgcn_mfma_f32_16x16x32_f16(a, b, c, 0, 0, 0)

// ================= CSR build: bucketed counting sort =================

__global__ __launch_bounds__(256) void k_hist(const int* __restrict__ dst,
                                              int* __restrict__ histCnt, int E) {
    __shared__ int h[NB_BUCKETS];
    for (int i = threadIdx.x; i < NB_BUCKETS; i += 256) h[i] = 0;
    __syncthreads();
    int base = blockIdx.x * EPB;
    for (int i = threadIdx.x; i < EPB; i += 256) {
        int e = base + i;
        if (e < E) atomicAdd(&h[((unsigned)dst[e]) >> 8], 1);
    }
    __syncthreads();
    for (int i = threadIdx.x; i < NB_BUCKETS; i += 256)
        if (h[i]) atomicAdd(&histCnt[i], h[i]);
}

__global__ __launch_bounds__(256) void k_scanB(const int* __restrict__ histCnt,
                                               int* __restrict__ bucketBase,
                                               int* __restrict__ bucketCursor) {
    __shared__ int s[512];
    int t = threadIdx.x;
    s[t] = (t < NB_BUCKETS) ? histCnt[t] : 0;
    s[t + 256] = (t + 256 < NB_BUCKETS) ? histCnt[t + 256] : 0;
    __syncthreads();
    for (int off = 1; off < 512; off <<= 1) {
        int v0 = (t >= off) ? s[t - off] : 0;
        int v1 = (t + 256 >= off) ? s[t + 256 - off] : 0;
        __syncthreads();
        s[t] += v0;
        s[t + 256] += v1;
        __syncthreads();
    }
    for (int i = t; i < NB_BUCKETS + 1; i += 256) {
        int base = (i == 0) ? 0 : s[i - 1];
        bucketBase[i] = base;
        if (i < NB_BUCKETS) bucketCursor[i] = base;
    }
}

__global__ __launch_bounds__(256) void k_partition(const int* __restrict__ src,
                                                   const int* __restrict__ dst,
                                                   int* __restrict__ bucketCursor,
                                                   unsigned* __restrict__ packed, int E) {
    __shared__ int h[NB_BUCKETS];
    __shared__ int cur[NB_BUCKETS];
    for (int i = threadIdx.x; i < NB_BUCKETS; i += 256) h[i] = 0;
    __syncthreads();
    int base = blockIdx.x * EPB;
    for (int i = threadIdx.x; i < EPB; i += 256) {
        int e = base + i;
        if (e < E) atomicAdd(&h[((unsigned)dst[e]) >> 8], 1);
    }
    __syncthreads();
    for (int i = threadIdx.x; i < NB_BUCKETS; i += 256)
        cur[i] = h[i] ? atomicAdd(&bucketCursor[i], h[i]) : 0;
    __syncthreads();
    for (int i = threadIdx.x; i < EPB; i += 256) {
        int e = base + i;
        if (e < E) {
            unsigned d = (unsigned)dst[e];
            unsigned b = d >> 8;
            int pos = atomicAdd(&cur[b], 1);
            packed[pos] = ((d & 255u) << 24) | (unsigned)src[e];
        }
    }
}

__global__ __launch_bounds__(256) void k_bucket(const unsigned* __restrict__ packed,
                                                const int* __restrict__ bucketBase,
                                                int* __restrict__ deg,
                                                int* __restrict__ offs,
                                                float* __restrict__ dinv,
                                                int* __restrict__ csr, int N) {
    __shared__ int hist[256];
    __shared__ int cur[256];
    int b = blockIdx.x, t = threadIdx.x;
    int lo = bucketBase[b], hi = bucketBase[b + 1];
    hist[t] = 0;
    __syncthreads();
    for (int i = lo + t; i < hi; i += 256)
        atomicAdd(&hist[packed[i] >> 24], 1);
    __syncthreads();
    int myDeg = hist[t];
    for (int off = 1; off < 256; off <<= 1) {
        int v = (t >= off) ? hist[t - off] : 0;
        __syncthreads();
        hist[t] += v;
        __syncthreads();
    }
    int excl = hist[t] - myDeg;
    cur[t] = lo + excl;
    int node = (b << 8) + t;
    if (node < N) {
        deg[node] = myDeg;
        offs[node] = lo + excl;
        dinv[node] = 1.0f / (float)(myDeg > 0 ? myDeg : 1);
    }
    __syncthreads();
    for (int i = lo + t; i < hi; i += 256) {
        unsigned w = packed[i];
        int pos = atomicAdd(&cur[w >> 24], 1);
        csr[pos] = (int)(w & 0x00FFFFFFu);
    }
}

// ---------------- pack W into B-fragment order, fp16 hi + fp16 residual ----------------
// B-frag: lane l holds B[k = c*32 + (l>>4)*8 + j][n = ct*16 + (l&15)]
// packed elem index: ((ct*4 + c)*64 + lane)*8 + j

__global__ void k_packW(const float* __restrict__ W0, const float* __restrict__ W1,
                        const float* __restrict__ W2, const float* __restrict__ W3,
                        const float* __restrict__ W4, const float* __restrict__ W5,
                        _Float16* __restrict__ Whi, _Float16* __restrict__ Wlo) {
    int m = blockIdx.y;
    const float* W; int Fo, nct, off;
    switch (m) {
        case 0: W = W0; Fo = 128; nct = 8; off = 0;     break;
        case 1: W = W1; Fo = 128; nct = 8; off = 16384; break;
        case 2: W = W2; Fo = 128; nct = 8; off = 32768; break;
        case 3: W = W3; Fo = 128; nct = 8; off = 49152; break;
        case 4: W = W4; Fo = 47;  nct = 3; off = 65536; break;
        default:W = W5; Fo = 47;  nct = 3; off = 71680; break;
    }
    int e = blockIdx.x * 256 + threadIdx.x;
    if (e >= nct * 2048) return;
    int j = e & 7, lane = (e >> 3) & 63, c = (e >> 9) & 3, ct = e >> 11;
    int k = c * 32 + (lane >> 4) * 8 + j;
    int n = ct * 16 + (lane & 15);
    float v = (n < Fo) ? W[(size_t)k * Fo + n] : 0.f;
    _Float16 h = (_Float16)v;
    Whi[off + e] = h;
    Wlo[off + e] = (_Float16)(v - (float)h);
}

// ---------------- cast x (fp32 row-major) into packed fp16 A-frag order ----------------

__global__ void k_castA(const float* __restrict__ A, _Float16* __restrict__ Ap, int N) {
    int t = blockIdx.x * 256 + threadIdx.x;
    if (t >= N * 64) return;
    int n = t >> 6;
    int kp = (t & 63) * 2;
    float2 v = *(const float2*)(A + (size_t)n * 128 + kp);
    int rt = n >> 4, mm = n & 15;
    int c = kp >> 5, q = (kp & 31) >> 3, j = kp & 7;
    size_t idx = ((size_t)(rt * 4 + c) * 64 + q * 16 + mm) * 8 + j;
    *(f16x2*)(Ap + idx) = (f16x2){(_Float16)v.x, (_Float16)v.y};
}

// ---------------- MFMA dual GEMM, Fo=128 ----------------

__global__ __launch_bounds__(256) void k_gemm128(const _Float16* __restrict__ Ap,
                                                 const _Float16* __restrict__ WsHi,
                                                 const _Float16* __restrict__ WsLo,
                                                 const _Float16* __restrict__ WnHi,
                                                 const _Float16* __restrict__ WnLo,
                                                 const float* __restrict__ bias,
                                                 _Float16* __restrict__ hs,
                                                 _Float16* __restrict__ hw, int N) {
    int tid = threadIdx.x;
    int w = tid >> 6, l = tid & 63;
    int rb = blockIdx.x;
    int path = w >> 1, cg = w & 1;
    const _Float16* BH = path ? WnHi : WsHi;
    const _Float16* BL = path ? WnLo : WsLo;

    f32x4 acc[2][4];
#pragma unroll
    for (int i = 0; i < 2; ++i)
#pragma unroll
        for (int j = 0; j < 4; ++j) acc[i][j] = (f32x4){0.f, 0.f, 0.f, 0.f};

#pragma unroll
    for (int c = 0; c < 4; ++c) {
        f16x8 a[2], bh[4], bl[4];
#pragma unroll
        for (int rt = 0; rt < 2; ++rt) {
            size_t ai = (((size_t)(rb * 2 + rt) * 4 + c) * 64 + l) * 8;
            a[rt] = *(const f16x8*)(Ap + ai);
        }
#pragma unroll
        for (int ct = 0; ct < 4; ++ct) {
            size_t bi = (((size_t)(cg * 4 + ct) * 4 + c) * 64 + l) * 8;
            bh[ct] = *(const f16x8*)(BH + bi);
            bl[ct] = *(const f16x8*)(BL + bi);
        }
#pragma unroll
        for (int rt = 0; rt < 2; ++rt)
#pragma unroll
            for (int ct = 0; ct < 4; ++ct) {
                acc[rt][ct] = MFMAH(a[rt], bh[ct], acc[rt][ct]);
                acc[rt][ct] = MFMAH(a[rt], bl[ct], acc[rt][ct]);
            }
    }

    // C/D layout: col = l&15, row = (l>>4)*4 + r   [verified m89/m91]
    int q = l >> 4, n15 = l & 15;
#pragma unroll
    for (int ct = 0; ct < 4; ++ct) {
        int col = (cg * 4 + ct) * 16 + n15;
        float b = (path == 0) ? bias[col] : 0.f;
#pragma unroll
        for (int rt = 0; rt < 2; ++rt) {
            int rbase = rb * 32 + rt * 16 + q * 4;
#pragma unroll
            for (int r = 0; r < 4; ++r) {
                int row = rbase + r;
                if (path == 0)
                    hs[(size_t)row * 128 + col] = (_Float16)(acc[rt][ct][r] + b);
                else
                    hw[(size_t)row * 128 + col] = (_Float16)acc[rt][ct][r];
            }
        }
    }
}

// ---------------- MFMA dual GEMM, Fo=47 (padded 48) ----------------

__global__ __launch_bounds__(256) void k_gemm47(const _Float16* __restrict__ Ap,
                                                const _Float16* __restrict__ WsHi,
                                                const _Float16* __restrict__ WsLo,
                                                const _Float16* __restrict__ WnHi,
                                                const _Float16* __restrict__ WnLo,
                                                const float* __restrict__ bias,
                                                _Float16* __restrict__ hs48,
                                                _Float16* __restrict__ hw48, int N) {
    int tid = threadIdx.x;
    int w = tid >> 6, l = tid & 63;
    int rb = blockIdx.x;
    int path = w & 1, rh = w >> 1;
    const _Float16* BH = path ? WnHi : WsHi;
    const _Float16* BL = path ? WnLo : WsLo;

    f32x4 acc[2][3];
#pragma unroll
    for (int i = 0; i < 2; ++i)
#pragma unroll
        for (int j = 0; j < 3; ++j) acc[i][j] = (f32x4){0.f, 0.f, 0.f, 0.f};

#pragma unroll
    for (int c = 0; c < 4; ++c) {
        f16x8 a[2], bh[3], bl[3];
#pragma unroll
        for (int rt = 0; rt < 2; ++rt) {
            size_t ai = (((size_t)(rb * 4 + rh * 2 + rt) * 4 + c) * 64 + l) * 8;
            a[rt] = *(const f16x8*)(Ap + ai);
        }
#pragma unroll
        for (int ct = 0; ct < 3; ++ct) {
            size_t bi = (((size_t)ct * 4 + c) * 64 + l) * 8;
            bh[ct] = *(const f16x8*)(BH + bi);
            bl[ct] = *(const f16x8*)(BL + bi);
        }
#pragma unroll
        for (int rt = 0; rt < 2; ++rt)
#pragma unroll
            for (int ct = 0; ct < 3; ++ct) {
                acc[rt][ct] = MFMAH(a[rt], bh[ct], acc[rt][ct]);
                acc[rt][ct] = MFMAH(a[rt], bl[ct], acc[rt][ct]);
            }
    }

    int q = l >> 4, n15 = l & 15;
#pragma unroll
    for (int ct = 0; ct < 3; ++ct) {
        int col = ct * 16 + n15;
        float b = (path == 0 && col < 47) ? bias[col] : 0.f;
#pragma unroll
        for (int rt = 0; rt < 2; ++rt) {
            int rbase = rb * 64 + rh * 32 + rt * 16 + q * 4;
#pragma unroll
            for (int r = 0; r < 4; ++r) {
                int row = rbase + r;
                if (row >= N) continue;
                if (path == 0)
                    hs48[(size_t)row * 48 + col] = (_Float16)(acc[rt][ct][r] + b);
                else
                    hw48[(size_t)row * 48 + col] = (_Float16)acc[rt][ct][r];
            }
        }
    }
}

// ---------------- combine (mid): vector-index gather, 16 rows in flight ----------------
// One wave per node. 64 neighbor indices arrive in ONE coalesced load; __shfl
// broadcasts each index -> 16 independent 256 B gathers in flight, no scalar-
// load stalls in the chain.

__global__ __launch_bounds__(256) void k_combine_mid(const __half2* __restrict__ hs,
                                                     const __half2* __restrict__ hw,
                                                     const int* __restrict__ csr,
                                                     const int* __restrict__ offs,
                                                     const int* __restrict__ deg,
                                                     const float* __restrict__ dinv,
                                                     __half* __restrict__ Ap, int N) {
    int wid = (blockIdx.x * 256 + threadIdx.x) >> 6;
    int l = threadIdx.x & 63;
    if (wid >= N) return;
    int beg = __builtin_amdgcn_readfirstlane(offs[wid]);
    int d   = __builtin_amdgcn_readfirstlane(deg[wid]);
    float2 s = __half22float2(hs[(size_t)wid * 64 + l]);  // independent, issues early
    float acc0 = 0.f, acc1 = 0.f;
    for (int base = 0; base < d; base += 64) {
        int nv = d - base; if (nv > 64) nv = 64;
        int idxv = csr[beg + base + ((l < nv) ? l : 0)];  // one 256 B coalesced load
        for (int e = 0; e < nv; e += 16) {
            float2 c[16];
#pragma unroll
            for (int i = 0; i < 16; ++i) {
                int u = __shfl(idxv, e + i);  // lanes >= nv hold clamped-valid idx
                c[i] = __half22float2(hw[(size_t)u * 64 + l]);
            }
#pragma unroll
            for (int i = 0; i < 16; ++i) {
                float m = (base + e + i < d) ? 1.f : 0.f;
                acc0 = fmaf(m, c[i].x, acc0);
                acc1 = fmaf(m, c[i].y, acc1);
            }
        }
    }
    float di = dinv[wid];
    float v0 = fmaxf(s.x + di * acc0, 0.f);
    float v1 = fmaxf(s.y + di * acc1, 0.f);

    int rt = wid >> 4, mm = wid & 15;
    int k0 = l * 2;
    int c4 = k0 >> 5, q = (k0 & 31) >> 3, j = k0 & 7;
    size_t idx = ((size_t)(rt * 4 + c4) * 64 + q * 16 + mm) * 8 + j;
    *(__half2*)(Ap + idx) = __floats2half2_rn(v0, v1);
}

// ---------------- combine (final, Fo=47): vector-index gather, fp32 out ----------------
// All 64 lanes stay active (shfl validity); lanes >= 24 clamp to feature 23 and
// are masked at the store.

__global__ __launch_bounds__(256) void k_combine_final(const __half2* __restrict__ hs48,
                                                       const __half2* __restrict__ hw48,
                                                       const int* __restrict__ csr,
                                                       const int* __restrict__ offs,
                                                       const int* __restrict__ deg,
                                                       const float* __restrict__ dinv,
                                                       float* __restrict__ out, int N) {
    int wid = (blockIdx.x * 256 + threadIdx.x) >> 6;
    int l = threadIdx.x & 63;
    if (wid >= N) return;
    int beg = __builtin_amdgcn_readfirstlane(offs[wid]);
    int d   = __builtin_amdgcn_readfirstlane(deg[wid]);
    int lc = (l < 24) ? l : 23;  // keep all lanes active for __shfl
    float2 s = __half22float2(hs48[(size_t)wid * 24 + lc]);
    float acc0 = 0.f, acc1 = 0.f;
    for (int base = 0; base < d; base += 64) {
        int nv = d - base; if (nv > 64) nv = 64;
        int idxv = csr[beg + base + ((l < nv) ? l : 0)];
        for (int e = 0; e < nv; e += 16) {
            float2 c[16];
#pragma unroll
            for (int i = 0; i < 16; ++i) {
                int u = __shfl(idxv, e + i);
                c[i] = __half22float2(hw48[(size_t)u * 24 + lc]);
            }
#pragma unroll
            for (int i = 0; i < 16; ++i) {
                float m = (base + e + i < d) ? 1.f : 0.f;
                acc0 = fmaf(m, c[i].x, acc0);
                acc1 = fmaf(m, c[i].y, acc1);
            }
        }
    }
    float di = dinv[wid];
    if (l < 24) {
        int f0 = l * 2, f1 = l * 2 + 1;
        out[(size_t)wid * 47 + f0] = s.x + di * acc0;
        if (f1 < 47) out[(size_t)wid * 47 + f1] = s.y + di * acc1;
    }
}

// ---------------- launch ----------------

extern "C" void kernel_launch(void* const* d_in, const int* in_sizes, int n_in,
                              void* d_out, int out_size, void* d_ws, size_t ws_size,
                              hipStream_t stream) {
    const int N = NN, E = NE;
    const float* x   = (const float*)d_in[0];
    const int*   src = (const int*)d_in[1];
    const int*   dst = (const int*)d_in[2];
    const float* Ws0 = (const float*)d_in[3];
    const float* Wn0 = (const float*)d_in[4];
    const float* b0  = (const float*)d_in[5];
    const float* Ws1 = (const float*)d_in[6];
    const float* Wn1 = (const float*)d_in[7];
    const float* b1  = (const float*)d_in[8];
    const float* Ws2 = (const float*)d_in[9];
    const float* Wn2 = (const float*)d_in[10];
    const float* b2  = (const float*)d_in[11];
    float* out = (float*)d_out;

    char* p = (char*)d_ws;
    size_t o = 0;
    auto alloc = [&](size_t bytes) -> void* {
        void* q = p + o;
        o = (o + bytes + 511) & ~(size_t)511;
        return q;
    };
    const size_t RTPAD = 6252;  // rowtiles of 16: 6250 used + pad to gemm47 block span
    int*      deg     = (int*)alloc((size_t)N * 4);
    int*      offs    = (int*)alloc((size_t)N * 4);
    float*    dinv    = (float*)alloc((size_t)N * 4);
    int*      histCnt = (int*)alloc(NB_BUCKETS * 4);
    int*      bBase   = (int*)alloc((NB_BUCKETS + 1) * 4);
    int*      bCur    = (int*)alloc(NB_BUCKETS * 4);
    unsigned* packed  = (unsigned*)alloc((size_t)E * 4);
    int*      csr     = (int*)alloc((size_t)E * 4 + 256);  // +pad: vector idx load may read past end
    _Float16* Ahp     = (_Float16*)alloc(RTPAD * 2048 * 2);
    _Float16* hs      = (_Float16*)alloc((size_t)N * 128 * 2);
    _Float16* hw      = (_Float16*)alloc((size_t)N * 128 * 2);
    _Float16* Whi     = (_Float16*)alloc(77824 * 2);
    _Float16* Wlo     = (_Float16*)alloc(77824 * 2);

    // ---- CSR build: hist -> scan -> partition -> per-bucket sort ----
    hipMemsetAsync(histCnt, 0, NB_BUCKETS * 4, stream);
    int pgrid = (E + EPB - 1) / EPB;  // 196
    k_hist<<<pgrid, 256, 0, stream>>>(dst, histCnt, E);
    k_scanB<<<1, 256, 0, stream>>>(histCnt, bBase, bCur);
    k_partition<<<pgrid, 256, 0, stream>>>(src, dst, bCur, packed, E);
    k_bucket<<<NB_BUCKETS, 256, 0, stream>>>(packed, bBase, deg, offs, dinv, csr, N);

    // ---- pack weights + cast input ----
    k_packW<<<dim3(64, 6), 256, 0, stream>>>(Ws0, Wn0, Ws1, Wn1, Ws2, Wn2, Whi, Wlo);
    k_castA<<<(N * 64 + 255) / 256, 256, 0, stream>>>(x, Ahp, N);

    int g128 = N / 32;           // 3125 (N % 32 == 0)
    int g47  = (N + 63) / 64;    // 1563
    int cwg  = (N * 64 + 255) / 256;

    // ---- layer 0 ----
    k_gemm128<<<g128, 256, 0, stream>>>(Ahp, Whi, Wlo, Whi + 16384, Wlo + 16384,
                                        b0, hs, hw, N);
    k_combine_mid<<<cwg, 256, 0, stream>>>((const __half2*)hs, (const __half2*)hw, csr,
                                           offs, deg, dinv, (__half*)Ahp, N);
    // ---- layer 1 ----
    k_gemm128<<<g128, 256, 0, stream>>>(Ahp, Whi + 32768, Wlo + 32768,
                                        Whi + 49152, Wlo + 49152, b1, hs, hw, N);
    k_combine_mid<<<cwg, 256, 0, stream>>>((const __half2*)hs, (const __half2*)hw, csr,
                                           offs, deg, dinv, (__half*)Ahp, N);
    // ---- layer 2 (Fo=47, padded 48) ----
    k_gemm47<<<g47, 256, 0, stream>>>(Ahp, Whi + 65536, Wlo + 65536,
                                      Whi + 71680, Wlo + 71680, b2, hs, hw, N);
    k_combine_final<<<cwg, 256, 0, stream>>>((const __half2*)hs, (const __half2*)hw, csr,
                                             offs, deg, dinv, out, N);
}

// Round 8
// 421.815 us; speedup vs baseline: 2.8863x; 1.0010x over previous
//
#include <hip/hip_runtime.h>
#include <hip/hip_fp16.h>

#define NN 100000
#define NE 1600000
#define NB_BUCKETS 391   // ceil(100000 / 256); bucket = 256 consecutive dst nodes
#define EPB 8192         // edges per partition block

typedef __attribute__((ext_vector_type(8))) _Float16 f16x8;
typedef __attribute__((ext_vector_type(2))) _Float16 f16x2;
typedef __attribute__((ext_vector_type(4))) float f32x4;
#define MFMAH(a, b, c) __builtin_amdgcn_mfma_f32_16x16x32_f16(a, b, c, 0, 0, 0)

// ================= CSR build: bucketed counting sort =================

__global__ __launch_bounds__(256) void k_hist(const int* __restrict__ dst,
                                              int* __restrict__ histCnt, int E) {
    __shared__ int h[NB_BUCKETS];
    for (int i = threadIdx.x; i < NB_BUCKETS; i += 256) h[i] = 0;
    __syncthreads();
    int base = blockIdx.x * EPB;
    for (int i = threadIdx.x; i < EPB; i += 256) {
        int e = base + i;
        if (e < E) atomicAdd(&h[((unsigned)dst[e]) >> 8], 1);
    }
    __syncthreads();
    for (int i = threadIdx.x; i < NB_BUCKETS; i += 256)
        if (h[i]) atomicAdd(&histCnt[i], h[i]);
}

__global__ __launch_bounds__(256) void k_scanB(const int* __restrict__ histCnt,
                                               int* __restrict__ bucketBase,
                                               int* __restrict__ bucketCursor) {
    __shared__ int s[512];
    int t = threadIdx.x;
    s[t] = (t < NB_BUCKETS) ? histCnt[t] : 0;
    s[t + 256] = (t + 256 < NB_BUCKETS) ? histCnt[t + 256] : 0;
    __syncthreads();
    for (int off = 1; off < 512; off <<= 1) {
        int v0 = (t >= off) ? s[t - off] : 0;
        int v1 = (t + 256 >= off) ? s[t + 256 - off] : 0;
        __syncthreads();
        s[t] += v0;
        s[t + 256] += v1;
        __syncthreads();
    }
    for (int i = t; i < NB_BUCKETS + 1; i += 256) {
        int base = (i == 0) ? 0 : s[i - 1];
        bucketBase[i] = base;
        if (i < NB_BUCKETS) bucketCursor[i] = base;
    }
}

__global__ __launch_bounds__(256) void k_partition(const int* __restrict__ src,
                                                   const int* __restrict__ dst,
                                                   int* __restrict__ bucketCursor,
                                                   unsigned* __restrict__ packed, int E) {
    __shared__ int h[NB_BUCKETS];
    __shared__ int cur[NB_BUCKETS];
    for (int i = threadIdx.x; i < NB_BUCKETS; i += 256) h[i] = 0;
    __syncthreads();
    int base = blockIdx.x * EPB;
    for (int i = threadIdx.x; i < EPB; i += 256) {
        int e = base + i;
        if (e < E) atomicAdd(&h[((unsigned)dst[e]) >> 8], 1);
    }
    __syncthreads();
    for (int i = threadIdx.x; i < NB_BUCKETS; i += 256)
        cur[i] = h[i] ? atomicAdd(&bucketCursor[i], h[i]) : 0;
    __syncthreads();
    for (int i = threadIdx.x; i < EPB; i += 256) {
        int e = base + i;
        if (e < E) {
            unsigned d = (unsigned)dst[e];
            unsigned b = d >> 8;
            int pos = atomicAdd(&cur[b], 1);
            packed[pos] = ((d & 255u) << 24) | (unsigned)src[e];
        }
    }
}

__global__ __launch_bounds__(256) void k_bucket(const unsigned* __restrict__ packed,
                                                const int* __restrict__ bucketBase,
                                                int* __restrict__ deg,
                                                int* __restrict__ offs,
                                                float* __restrict__ dinv,
                                                int* __restrict__ csr, int N) {
    __shared__ int hist[256];
    __shared__ int cur[256];
    int b = blockIdx.x, t = threadIdx.x;
    int lo = bucketBase[b], hi = bucketBase[b + 1];
    hist[t] = 0;
    __syncthreads();
    for (int i = lo + t; i < hi; i += 256)
        atomicAdd(&hist[packed[i] >> 24], 1);
    __syncthreads();
    int myDeg = hist[t];
    for (int off = 1; off < 256; off <<= 1) {
        int v = (t >= off) ? hist[t - off] : 0;
        __syncthreads();
        hist[t] += v;
        __syncthreads();
    }
    int excl = hist[t] - myDeg;
    cur[t] = lo + excl;
    int node = (b << 8) + t;
    if (node < N) {
        deg[node] = myDeg;
        offs[node] = lo + excl;
        dinv[node] = 1.0f / (float)(myDeg > 0 ? myDeg : 1);
    }
    __syncthreads();
    for (int i = lo + t; i < hi; i += 256) {
        unsigned w = packed[i];
        int pos = atomicAdd(&cur[w >> 24], 1);
        csr[pos] = (int)(w & 0x00FFFFFFu);
    }
}

// ---------------- pack W into B-fragment order, fp16 hi + fp16 residual ----------------
// B-frag: lane l holds B[k = c*32 + (l>>4)*8 + j][n = ct*16 + (l&15)]
// packed elem index: ((ct*4 + c)*64 + lane)*8 + j

__global__ void k_packW(const float* __restrict__ W0, const float* __restrict__ W1,
                        const float* __restrict__ W2, const float* __restrict__ W3,
                        const float* __restrict__ W4, const float* __restrict__ W5,
                        _Float16* __restrict__ Whi, _Float16* __restrict__ Wlo) {
    int m = blockIdx.y;
    const float* W; int Fo, nct, off;
    switch (m) {
        case 0: W = W0; Fo = 128; nct = 8; off = 0;     break;
        case 1: W = W1; Fo = 128; nct = 8; off = 16384; break;
        case 2: W = W2; Fo = 128; nct = 8; off = 32768; break;
        case 3: W = W3; Fo = 128; nct = 8; off = 49152; break;
        case 4: W = W4; Fo = 47;  nct = 3; off = 65536; break;
        default:W = W5; Fo = 47;  nct = 3; off = 71680; break;
    }
    int e = blockIdx.x * 256 + threadIdx.x;
    if (e >= nct * 2048) return;
    int j = e & 7, lane = (e >> 3) & 63, c = (e >> 9) & 3, ct = e >> 11;
    int k = c * 32 + (lane >> 4) * 8 + j;
    int n = ct * 16 + (lane & 15);
    float v = (n < Fo) ? W[(size_t)k * Fo + n] : 0.f;
    _Float16 h = (_Float16)v;
    Whi[off + e] = h;
    Wlo[off + e] = (_Float16)(v - (float)h);
}

// ---------------- cast x (fp32 row-major) into packed fp16 A-frag order ----------------

__global__ void k_castA(const float* __restrict__ A, _Float16* __restrict__ Ap, int N) {
    int t = blockIdx.x * 256 + threadIdx.x;
    if (t >= N * 64) return;
    int n = t >> 6;
    int kp = (t & 63) * 2;
    float2 v = *(const float2*)(A + (size_t)n * 128 + kp);
    int rt = n >> 4, mm = n & 15;
    int c = kp >> 5, q = (kp & 31) >> 3, j = kp & 7;
    size_t idx = ((size_t)(rt * 4 + c) * 64 + q * 16 + mm) * 8 + j;
    *(f16x2*)(Ap + idx) = (f16x2){(_Float16)v.x, (_Float16)v.y};
}

// ---------------- MFMA dual GEMM, Fo=128 ----------------

__global__ __launch_bounds__(256) void k_gemm128(const _Float16* __restrict__ Ap,
                                                 const _Float16* __restrict__ WsHi,
                                                 const _Float16* __restrict__ WsLo,
                                                 const _Float16* __restrict__ WnHi,
                                                 const _Float16* __restrict__ WnLo,
                                                 const float* __restrict__ bias,
                                                 _Float16* __restrict__ hs,
                                                 _Float16* __restrict__ hw, int N) {
    int tid = threadIdx.x;
    int w = tid >> 6, l = tid & 63;
    int rb = blockIdx.x;
    int path = w >> 1, cg = w & 1;
    const _Float16* BH = path ? WnHi : WsHi;
    const _Float16* BL = path ? WnLo : WsLo;

    f32x4 acc[2][4];
#pragma unroll
    for (int i = 0; i < 2; ++i)
#pragma unroll
        for (int j = 0; j < 4; ++j) acc[i][j] = (f32x4){0.f, 0.f, 0.f, 0.f};

#pragma unroll
    for (int c = 0; c < 4; ++c) {
        f16x8 a[2], bh[4], bl[4];
#pragma unroll
        for (int rt = 0; rt < 2; ++rt) {
            size_t ai = (((size_t)(rb * 2 + rt) * 4 + c) * 64 + l) * 8;
            a[rt] = *(const f16x8*)(Ap + ai);
        }
#pragma unroll
        for (int ct = 0; ct < 4; ++ct) {
            size_t bi = (((size_t)(cg * 4 + ct) * 4 + c) * 64 + l) * 8;
            bh[ct] = *(const f16x8*)(BH + bi);
            bl[ct] = *(const f16x8*)(BL + bi);
        }
#pragma unroll
        for (int rt = 0; rt < 2; ++rt)
#pragma unroll
            for (int ct = 0; ct < 4; ++ct) {
                acc[rt][ct] = MFMAH(a[rt], bh[ct], acc[rt][ct]);
                acc[rt][ct] = MFMAH(a[rt], bl[ct], acc[rt][ct]);
            }
    }

    // C/D layout: col = l&15, row = (l>>4)*4 + r   [verified m89/m91]
    int q = l >> 4, n15 = l & 15;
#pragma unroll
    for (int ct = 0; ct < 4; ++ct) {
        int col = (cg * 4 + ct) * 16 + n15;
        float b = (path == 0) ? bias[col] : 0.f;
#pragma unroll
        for (int rt = 0; rt < 2; ++rt) {
            int rbase = rb * 32 + rt * 16 + q * 4;
#pragma unroll
            for (int r = 0; r < 4; ++r) {
                int row = rbase + r;
                if (path == 0)
                    hs[(size_t)row * 128 + col] = (_Float16)(acc[rt][ct][r] + b);
                else
                    hw[(size_t)row * 128 + col] = (_Float16)acc[rt][ct][r];
            }
        }
    }
}

// ---------------- MFMA dual GEMM, Fo=47 (rows padded to 64 for 16B-lane combine) -------

__global__ __launch_bounds__(256) void k_gemm47(const _Float16* __restrict__ Ap,
                                                const _Float16* __restrict__ WsHi,
                                                const _Float16* __restrict__ WsLo,
                                                const _Float16* __restrict__ WnHi,
                                                const _Float16* __restrict__ WnLo,
                                                const float* __restrict__ bias,
                                                _Float16* __restrict__ hs64,
                                                _Float16* __restrict__ hw64, int N) {
    int tid = threadIdx.x;
    int w = tid >> 6, l = tid & 63;
    int rb = blockIdx.x;
    int path = w & 1, rh = w >> 1;
    const _Float16* BH = path ? WnHi : WsHi;
    const _Float16* BL = path ? WnLo : WsLo;

    f32x4 acc[2][3];
#pragma unroll
    for (int i = 0; i < 2; ++i)
#pragma unroll
        for (int j = 0; j < 3; ++j) acc[i][j] = (f32x4){0.f, 0.f, 0.f, 0.f};

#pragma unroll
    for (int c = 0; c < 4; ++c) {
        f16x8 a[2], bh[3], bl[3];
#pragma unroll
        for (int rt = 0; rt < 2; ++rt) {
            size_t ai = (((size_t)(rb * 4 + rh * 2 + rt) * 4 + c) * 64 + l) * 8;
            a[rt] = *(const f16x8*)(Ap + ai);
        }
#pragma unroll
        for (int ct = 0; ct < 3; ++ct) {
            size_t bi = (((size_t)ct * 4 + c) * 64 + l) * 8;
            bh[ct] = *(const f16x8*)(BH + bi);
            bl[ct] = *(const f16x8*)(BL + bi);
        }
#pragma unroll
        for (int rt = 0; rt < 2; ++rt)
#pragma unroll
            for (int ct = 0; ct < 3; ++ct) {
                acc[rt][ct] = MFMAH(a[rt], bh[ct], acc[rt][ct]);
                acc[rt][ct] = MFMAH(a[rt], bl[ct], acc[rt][ct]);
            }
    }

    int q = l >> 4, n15 = l & 15;
#pragma unroll
    for (int ct = 0; ct < 3; ++ct) {
        int col = ct * 16 + n15;
        float b = (path == 0 && col < 47) ? bias[col] : 0.f;
#pragma unroll
        for (int rt = 0; rt < 2; ++rt) {
            int rbase = rb * 64 + rh * 32 + rt * 16 + q * 4;
#pragma unroll
            for (int r = 0; r < 4; ++r) {
                int row = rbase + r;
                if (row >= N) continue;
                if (path == 0)
                    hs64[(size_t)row * 64 + col] = (_Float16)(acc[rt][ct][r] + b);
                else
                    hw64[(size_t)row * 64 + col] = (_Float16)acc[rt][ct][r];
            }
        }
    }
}

// ---------------- combine (mid): 4 rows per load instruction ----------------
// Wave = 4 groups x 16 lanes. Lane loads 16 B (8 features) of its group's row:
// one global_load_dwordx4 fetches 4 full rows (1 KB). shfl_xor butterfly sums
// the 4 group-partials; 16 lanes store one contiguous f16x8 in A-frag order.

__global__ __launch_bounds__(256) void k_combine_mid(const _Float16* __restrict__ hs,
                                                     const _Float16* __restrict__ hw,
                                                     const int* __restrict__ csr,
                                                     const int* __restrict__ offs,
                                                     const int* __restrict__ deg,
                                                     const float* __restrict__ dinv,
                                                     _Float16* __restrict__ Ap, int N) {
    int wid = (blockIdx.x * 256 + threadIdx.x) >> 6;
    int l = threadIdx.x & 63;
    if (wid >= N) return;
    int beg = __builtin_amdgcn_readfirstlane(offs[wid]);
    int d   = __builtin_amdgcn_readfirstlane(deg[wid]);
    int g = l >> 4, c = l & 15;

    f16x8 s;
    if (l < 16) s = *(const f16x8*)(hs + (size_t)wid * 128 + l * 8);  // issues early

    float acc[8];
#pragma unroll
    for (int j = 0; j < 8; ++j) acc[j] = 0.f;

    for (int base = 0; base < d; base += 64) {
        int nv = d - base; if (nv > 64) nv = 64;
        int idxv = csr[beg + base + ((l < nv) ? l : (nv - 1))];  // 256 B coalesced
        for (int e = 0; e < nv; e += 16) {
            f16x8 hv[4];
#pragma unroll
            for (int i = 0; i < 4; ++i) {
                int u = __shfl(idxv, e + i * 4 + g);
                hv[i] = *(const f16x8*)(hw + (size_t)u * 128 + c * 8);
            }
#pragma unroll
            for (int i = 0; i < 4; ++i) {
                float m = (base + e + i * 4 + g < d) ? 1.f : 0.f;
#pragma unroll
                for (int j = 0; j < 8; ++j)
                    acc[j] = fmaf((float)hv[i][j], m, acc[j]);  // v_fma_mix
            }
        }
    }
#pragma unroll
    for (int j = 0; j < 8; ++j) {
        acc[j] += __shfl_xor(acc[j], 16);
        acc[j] += __shfl_xor(acc[j], 32);
    }
    if (l < 16) {
        float di = dinv[wid];
        f16x8 o;
#pragma unroll
        for (int j = 0; j < 8; ++j)
            o[j] = (_Float16)fmaxf((float)s[j] + di * acc[j], 0.f);
        // features 8c..8c+7 = one contiguous j-run of the A-frag packing
        int rt = wid >> 4, mm = wid & 15;
        size_t idx = (((size_t)(rt * 4 + (c >> 2))) * 64 + (c & 3) * 16 + mm) * 8;
        *(f16x8*)(Ap + idx) = o;
    }
}

// ---------------- combine (final, Fo=47): 8 rows per load instruction ----------------
// Rows padded to 64 fp16; wave = 8 groups x 8 lanes, lane loads 16 B.
// Pad-column garbage (finite fp16) lands only in lanes c>=6, which never store.

__global__ __launch_bounds__(256) void k_combine_final(const _Float16* __restrict__ hs64,
                                                       const _Float16* __restrict__ hw64,
                                                       const int* __restrict__ csr,
                                                       const int* __restrict__ offs,
                                                       const int* __restrict__ deg,
                                                       const float* __restrict__ dinv,
                                                       float* __restrict__ out, int N) {
    int wid = (blockIdx.x * 256 + threadIdx.x) >> 6;
    int l = threadIdx.x & 63;
    if (wid >= N) return;
    int beg = __builtin_amdgcn_readfirstlane(offs[wid]);
    int d   = __builtin_amdgcn_readfirstlane(deg[wid]);
    int g = l >> 3, c = l & 7;

    f16x8 s;
    if (l < 6) s = *(const f16x8*)(hs64 + (size_t)wid * 64 + l * 8);

    float acc[8];
#pragma unroll
    for (int j = 0; j < 8; ++j) acc[j] = 0.f;

    for (int base = 0; base < d; base += 64) {
        int nv = d - base; if (nv > 64) nv = 64;
        int idxv = csr[beg + base + ((l < nv) ? l : (nv - 1))];
        for (int e = 0; e < nv; e += 16) {
            f16x8 hv[2];
#pragma unroll
            for (int i = 0; i < 2; ++i) {
                int u = __shfl(idxv, e + i * 8 + g);
                hv[i] = *(const f16x8*)(hw64 + (size_t)u * 64 + c * 8);
            }
#pragma unroll
            for (int i = 0; i < 2; ++i) {
                float m = (base + e + i * 8 + g < d) ? 1.f : 0.f;
#pragma unroll
                for (int j = 0; j < 8; ++j)
                    acc[j] = fmaf((float)hv[i][j], m, acc[j]);
            }
        }
    }
#pragma unroll
    for (int j = 0; j < 8; ++j) {
        acc[j] += __shfl_xor(acc[j], 8);
        acc[j] += __shfl_xor(acc[j], 16);
        acc[j] += __shfl_xor(acc[j], 32);
    }
    if (l < 6) {
        float di = dinv[wid];
#pragma unroll
        for (int j = 0; j < 8; ++j) {
            int f = l * 8 + j;
            if (f < 47) out[(size_t)wid * 47 + f] = (float)s[j] + di * acc[j];
        }
    }
}

// ---------------- launch ----------------

extern "C" void kernel_launch(void* const* d_in, const int* in_sizes, int n_in,
                              void* d_out, int out_size, void* d_ws, size_t ws_size,
                              hipStream_t stream) {
    const int N = NN, E = NE;
    const float* x   = (const float*)d_in[0];
    const int*   src = (const int*)d_in[1];
    const int*   dst = (const int*)d_in[2];
    const float* Ws0 = (const float*)d_in[3];
    const float* Wn0 = (const float*)d_in[4];
    const float* b0  = (const float*)d_in[5];
    const float* Ws1 = (const float*)d_in[6];
    const float* Wn1 = (const float*)d_in[7];
    const float* b1  = (const float*)d_in[8];
    const float* Ws2 = (const float*)d_in[9];
    const float* Wn2 = (const float*)d_in[10];
    const float* b2  = (const float*)d_in[11];
    float* out = (float*)d_out;

    char* p = (char*)d_ws;
    size_t o = 0;
    auto alloc = [&](size_t bytes) -> void* {
        void* q = p + o;
        o = (o + bytes + 511) & ~(size_t)511;
        return q;
    };
    const size_t RTPAD = 6252;  // rowtiles of 16: 6250 used + pad to gemm47 block span
    int*      deg     = (int*)alloc((size_t)N * 4);
    int*      offs    = (int*)alloc((size_t)N * 4);
    float*    dinv    = (float*)alloc((size_t)N * 4);
    int*      histCnt = (int*)alloc(NB_BUCKETS * 4);
    int*      bBase   = (int*)alloc((NB_BUCKETS + 1) * 4);
    int*      bCur    = (int*)alloc(NB_BUCKETS * 4);
    unsigned* packed  = (unsigned*)alloc((size_t)E * 4);
    int*      csr     = (int*)alloc((size_t)E * 4 + 256);
    _Float16* Ahp     = (_Float16*)alloc(RTPAD * 2048 * 2);
    _Float16* hs      = (_Float16*)alloc((size_t)N * 128 * 2);
    _Float16* hw      = (_Float16*)alloc((size_t)N * 128 * 2);
    _Float16* Whi     = (_Float16*)alloc(77824 * 2);
    _Float16* Wlo     = (_Float16*)alloc(77824 * 2);

    // ---- CSR build: hist -> scan -> partition -> per-bucket sort ----
    hipMemsetAsync(histCnt, 0, NB_BUCKETS * 4, stream);
    int pgrid = (E + EPB - 1) / EPB;  // 196
    k_hist<<<pgrid, 256, 0, stream>>>(dst, histCnt, E);
    k_scanB<<<1, 256, 0, stream>>>(histCnt, bBase, bCur);
    k_partition<<<pgrid, 256, 0, stream>>>(src, dst, bCur, packed, E);
    k_bucket<<<NB_BUCKETS, 256, 0, stream>>>(packed, bBase, deg, offs, dinv, csr, N);

    // ---- pack weights + cast input ----
    k_packW<<<dim3(64, 6), 256, 0, stream>>>(Ws0, Wn0, Ws1, Wn1, Ws2, Wn2, Whi, Wlo);
    k_castA<<<(N * 64 + 255) / 256, 256, 0, stream>>>(x, Ahp, N);

    int g128 = N / 32;           // 3125 (N % 32 == 0)
    int g47  = (N + 63) / 64;    // 1563
    int cwg  = (N * 64 + 255) / 256;

    // ---- layer 0 ----
    k_gemm128<<<g128, 256, 0, stream>>>(Ahp, Whi, Wlo, Whi + 16384, Wlo + 16384,
                                        b0, hs, hw, N);
    k_combine_mid<<<cwg, 256, 0, stream>>>(hs, hw, csr, offs, deg, dinv, Ahp, N);
    // ---- layer 1 ----
    k_gemm128<<<g128, 256, 0, stream>>>(Ahp, Whi + 32768, Wlo + 32768,
                                        Whi + 49152, Wlo + 49152, b1, hs, hw, N);
    k_combine_mid<<<cwg, 256, 0, stream>>>(hs, hw, csr, offs, deg, dinv, Ahp, N);
    // ---- layer 2 (Fo=47, rows padded to 64) ----
    k_gemm47<<<g47, 256, 0, stream>>>(Ahp, Whi + 65536, Wlo + 65536,
                                      Whi + 71680, Wlo + 71680, b2, hs, hw, N);
    k_combine_final<<<cwg, 256, 0, stream>>>(hs, hw, csr, offs, deg, dinv, out, N);
}